// Round 1
// baseline (1097.094 us; speedup 1.0000x reference)
//
#include <hip/hip_runtime.h>
#include <math.h>

#define THREADS 256
#define BM 64
#define BN 128
#define BK 32
#define APAD 36   // A-tile row stride (floats): 16B-aligned rows, bank-spread reads

// ---------------------------------------------------------------------------
// K1: P[n, 0:512] = x[n] @ [W_sd | W_ds | W_l1_top | W_l1_bot] + bias
//     bias per group: b_sd, b_ds, b_l1, 0   (b_l1 folded into 'a' so the edge
//     kernel just does relu(a[s]+bb[d]))
// grid: (ceil(M/64), 4), block 256
// ---------------------------------------------------------------------------
__global__ __launch_bounds__(THREADS)
void gemm_node(const float* __restrict__ X, int M,
               const float* __restrict__ W_sd, const float* __restrict__ b_sd,
               const float* __restrict__ W_ds, const float* __restrict__ b_ds,
               const float* __restrict__ W_l1, const float* __restrict__ b_l1,
               float* __restrict__ P)
{
    __shared__ float As[BM][APAD];
    __shared__ float Bs[BK][BN];

    const int tid = threadIdx.x;
    const int m0  = blockIdx.x * BM;
    const int grp = blockIdx.y;

    const float* B;
    const float* bias;
    if (grp == 0)      { B = W_sd;               bias = b_sd; }
    else if (grp == 1) { B = W_ds;               bias = b_ds; }
    else if (grp == 2) { B = W_l1;               bias = b_l1; }
    else               { B = W_l1 + 128 * 128;   bias = nullptr; }

    const int ty = tid >> 4;   // 0..15 -> rows ty*4 .. ty*4+3
    const int tx = tid & 15;   // cols tx*8 .. tx*8+7

    float acc[4][8];
#pragma unroll
    for (int i = 0; i < 4; ++i)
#pragma unroll
        for (int j = 0; j < 8; ++j) acc[i][j] = 0.f;

    const int lrow = tid >> 3;   // 0..31
    const int lc4  = tid & 7;    // float4 slot in 32-wide k tile

    for (int k0 = 0; k0 < 128; k0 += BK) {
        // ---- stage A (64 x 32) ----
#pragma unroll
        for (int p = 0; p < 2; ++p) {
            int r  = lrow + p * 32;
            int gr = m0 + r; if (gr >= M) gr = M - 1;
            const float4 v = *(const float4*)(X + (size_t)gr * 128 + k0 + lc4 * 4);
            *(float4*)(&As[r][lc4 * 4]) = v;
        }
        // ---- stage B (32 x 128) ----
#pragma unroll
        for (int i = 0; i < 4; ++i) {
            int idx = tid + i * 256;
            int kr  = idx >> 5;        // 0..31
            int c4  = idx & 31;        // 0..31
            const float4 v = *(const float4*)(B + (size_t)(k0 + kr) * 128 + c4 * 4);
            *(float4*)(&Bs[kr][c4 * 4]) = v;
        }
        __syncthreads();

#pragma unroll
        for (int k = 0; k < BK; ++k) {
            float a[4];
#pragma unroll
            for (int i = 0; i < 4; ++i) a[i] = As[ty * 4 + i][k];
            const float4 b0 = *(const float4*)(&Bs[k][tx * 8]);
            const float4 b1 = *(const float4*)(&Bs[k][tx * 8 + 4]);
            const float bb[8] = {b0.x, b0.y, b0.z, b0.w, b1.x, b1.y, b1.z, b1.w};
#pragma unroll
            for (int i = 0; i < 4; ++i)
#pragma unroll
                for (int j = 0; j < 8; ++j)
                    acc[i][j] = fmaf(a[i], bb[j], acc[i][j]);
        }
        __syncthreads();
    }

#pragma unroll
    for (int i = 0; i < 4; ++i) {
        int gr = m0 + ty * 4 + i;
        if (gr < M) {
            float* dst = P + (size_t)gr * 512 + grp * 128 + tx * 8;
#pragma unroll
            for (int j = 0; j < 8; ++j) {
                float bv = bias ? bias[tx * 8 + j] : 0.f;
                dst[j] = acc[i][j] + bv;
            }
        }
    }
}

// ---------------------------------------------------------------------------
// K2: per-edge. 1 wave = 1 edge; lane l owns dims 2l,2l+1.
//   lcs = sigmoid( sum_j relu(a[s][j]+bb[d][j]) * W_l2[j] + b_l2 )
//   h_in[d]  += p_sd[s]*lcs*cnt ; h_out[s] += p_ds[d]*lcs*cnt (atomics)
//   in_deg[d] += cnt ; out_deg[s] += cnt
// ---------------------------------------------------------------------------
__global__ __launch_bounds__(THREADS)
void edge_kernel(const float* __restrict__ P,
                 const int* __restrict__ src, const int* __restrict__ dst,
                 const float* __restrict__ counts,
                 const float* __restrict__ W_l2, const float* __restrict__ b_l2,
                 float* __restrict__ h_in, float* __restrict__ h_out,
                 float* __restrict__ in_deg, float* __restrict__ out_deg,
                 int E)
{
    const int lane = threadIdx.x & 63;
    const int wid  = threadIdx.x >> 6;
    const int e    = blockIdx.x * 4 + wid;
    if (e >= E) return;

    const int   s = src[e];
    const int   d = dst[e];
    const float c = counts[e];

    const float2* Ps = (const float2*)(P + (size_t)s * 512);
    const float2* Pd = (const float2*)(P + (size_t)d * 512);

    const float2 av = Ps[128 + lane];   // 'a'  cols 256..383 (b_l1 folded in)
    const float2 bv = Pd[192 + lane];   // 'bb' cols 384..511
    const float  t0 = fmaxf(av.x + bv.x, 0.f);
    const float  t1 = fmaxf(av.y + bv.y, 0.f);
    const float2 w2 = *(const float2*)(W_l2 + 2 * lane);
    float part = t0 * w2.x + t1 * w2.y;
#pragma unroll
    for (int off = 32; off; off >>= 1) part += __shfl_xor(part, off);

    const float lcs = 1.f / (1.f + expf(-(part + b_l2[0])));
    const float w   = lcs * c;

    const float2 ps = Ps[lane];        // p_sd cols 0..127
    const float2 pd = Pd[64 + lane];   // p_ds cols 128..255

    atomicAdd(h_in  + (size_t)d * 128 + 2 * lane,     ps.x * w);
    atomicAdd(h_in  + (size_t)d * 128 + 2 * lane + 1, ps.y * w);
    atomicAdd(h_out + (size_t)s * 128 + 2 * lane,     pd.x * w);
    atomicAdd(h_out + (size_t)s * 128 + 2 * lane + 1, pd.y * w);
    if (lane == 0) {
        atomicAdd(in_deg  + d, c);
        atomicAdd(out_deg + s, c);
    }
}

// ---------------------------------------------------------------------------
// K4: G = relu( [h_in/max(in_deg,1) , h_out/max(out_deg,1)] @ W_g1 + b_g1 )
//     (deg division fused into A-tile load; K=256, one col-block BN=128)
// ---------------------------------------------------------------------------
__global__ __launch_bounds__(THREADS)
void gemm_gate(const float* __restrict__ h_in, const float* __restrict__ h_out,
               const float* __restrict__ in_deg, const float* __restrict__ out_deg,
               int M,
               const float* __restrict__ W_g1, const float* __restrict__ b_g1,
               float* __restrict__ G)
{
    __shared__ float As[BM][APAD];
    __shared__ float Bs[BK][BN];

    const int tid = threadIdx.x;
    const int m0  = blockIdx.x * BM;
    const int ty  = tid >> 4;
    const int tx  = tid & 15;

    float acc[4][8];
#pragma unroll
    for (int i = 0; i < 4; ++i)
#pragma unroll
        for (int j = 0; j < 8; ++j) acc[i][j] = 0.f;

    const int lrow = tid >> 3;
    const int lc4  = tid & 7;

    for (int k0 = 0; k0 < 256; k0 += BK) {
        const float* Hsrc = (k0 < 128) ? h_in : h_out;
        const float* Dsrc = (k0 < 128) ? in_deg : out_deg;
        const int    kk   = k0 & 127;
#pragma unroll
        for (int p = 0; p < 2; ++p) {
            int r  = lrow + p * 32;
            int gr = m0 + r; if (gr >= M) gr = M - 1;
            const float rdeg = 1.f / fmaxf(Dsrc[gr], 1.f);
            float4 v = *(const float4*)(Hsrc + (size_t)gr * 128 + kk + lc4 * 4);
            v.x *= rdeg; v.y *= rdeg; v.z *= rdeg; v.w *= rdeg;
            *(float4*)(&As[r][lc4 * 4]) = v;
        }
#pragma unroll
        for (int i = 0; i < 4; ++i) {
            int idx = tid + i * 256;
            int kr  = idx >> 5;
            int c4  = idx & 31;
            const float4 v = *(const float4*)(W_g1 + (size_t)(k0 + kr) * 128 + c4 * 4);
            *(float4*)(&Bs[kr][c4 * 4]) = v;
        }
        __syncthreads();

#pragma unroll
        for (int k = 0; k < BK; ++k) {
            float a[4];
#pragma unroll
            for (int i = 0; i < 4; ++i) a[i] = As[ty * 4 + i][k];
            const float4 b0 = *(const float4*)(&Bs[k][tx * 8]);
            const float4 b1 = *(const float4*)(&Bs[k][tx * 8 + 4]);
            const float bb[8] = {b0.x, b0.y, b0.z, b0.w, b1.x, b1.y, b1.z, b1.w};
#pragma unroll
            for (int i = 0; i < 4; ++i)
#pragma unroll
                for (int j = 0; j < 8; ++j)
                    acc[i][j] = fmaf(a[i], bb[j], acc[i][j]);
        }
        __syncthreads();
    }

#pragma unroll
    for (int i = 0; i < 4; ++i) {
        int gr = m0 + ty * 4 + i;
        if (gr < M) {
            float* dst = G + (size_t)gr * 128 + tx * 8;
#pragma unroll
            for (int j = 0; j < 8; ++j)
                dst[j] = fmaxf(acc[i][j] + b_g1[tx * 8 + j], 0.f);
        }
    }
}

// ---------------------------------------------------------------------------
// K5: gate = sigmoid(G[v]·W_g2 + b_g2);
//     out[v] = gate*h_in[v]/ideg + (1-gate)*h_out[v]/odeg + x[v]
// ---------------------------------------------------------------------------
__global__ __launch_bounds__(THREADS)
void finalize(const float* __restrict__ G,
              const float* __restrict__ W_g2, const float* __restrict__ b_g2,
              const float* __restrict__ h_in, const float* __restrict__ h_out,
              const float* __restrict__ in_deg, const float* __restrict__ out_deg,
              const float* __restrict__ x, float* __restrict__ out, int M)
{
    const int lane = threadIdx.x & 63;
    const int wid  = threadIdx.x >> 6;
    const int v    = blockIdx.x * 4 + wid;
    if (v >= M) return;

    const float2 g2 = *(const float2*)(G + (size_t)v * 128 + 2 * lane);
    const float2 w2 = *(const float2*)(W_g2 + 2 * lane);
    float part = g2.x * w2.x + g2.y * w2.y;
#pragma unroll
    for (int off = 32; off; off >>= 1) part += __shfl_xor(part, off);
    const float gate = 1.f / (1.f + expf(-(part + b_g2[0])));

    const float rin  = 1.f / fmaxf(in_deg[v], 1.f);
    const float rout = 1.f / fmaxf(out_deg[v], 1.f);

    float2 hi = *(const float2*)(h_in  + (size_t)v * 128 + 2 * lane);
    float2 ho = *(const float2*)(h_out + (size_t)v * 128 + 2 * lane);
    const float2 xv = *(const float2*)(x + (size_t)v * 128 + 2 * lane);

    float2 o;
    o.x = gate * hi.x * rin + (1.f - gate) * ho.x * rout + xv.x;
    o.y = gate * hi.y * rin + (1.f - gate) * ho.y * rout + xv.y;
    *(float2*)(out + (size_t)v * 128 + 2 * lane) = o;
}

// ---------------------------------------------------------------------------
extern "C" void kernel_launch(void* const* d_in, const int* in_sizes, int n_in,
                              void* d_out, int out_size, void* d_ws, size_t ws_size,
                              hipStream_t stream)
{
    const float* x     = (const float*)d_in[0];
    const int*   src   = (const int*)  d_in[1];
    const int*   dst   = (const int*)  d_in[2];
    const float* cnts  = (const float*)d_in[3];
    const float* W_sd  = (const float*)d_in[4];
    const float* b_sd  = (const float*)d_in[5];
    const float* W_ds  = (const float*)d_in[6];
    const float* b_ds  = (const float*)d_in[7];
    const float* W_l1  = (const float*)d_in[8];
    const float* b_l1  = (const float*)d_in[9];
    const float* W_l2  = (const float*)d_in[10];
    const float* b_l2  = (const float*)d_in[11];
    const float* W_g1  = (const float*)d_in[12];
    const float* b_g1  = (const float*)d_in[13];
    const float* W_g2  = (const float*)d_in[14];
    const float* b_g2  = (const float*)d_in[15];

    const int M = in_sizes[0] / 128;   // 50000 nodes
    const int E = in_sizes[1];         // ~499950 unique edges

    // workspace layout (floats):
    //   P     : M*512   (p_sd | p_ds | a | bb)   -- dead after edge_kernel
    //   h_in  : M*128
    //   h_out : M*128
    //   indeg : M
    //   outdeg: M
    //   G     : reuses P (M*128)
    float* ws     = (float*)d_ws;
    float* P      = ws;
    float* h_in   = P + (size_t)M * 512;
    float* h_out  = h_in + (size_t)M * 128;
    float* indeg  = h_out + (size_t)M * 128;
    float* outdeg = indeg + M;
    float* G      = P;

    // zero accumulators (h_in, h_out, indeg, outdeg are contiguous)
    hipMemsetAsync(h_in, 0, ((size_t)M * 256 + 2 * (size_t)M) * sizeof(float), stream);

    dim3 g1((M + BM - 1) / BM, 4);
    gemm_node<<<g1, THREADS, 0, stream>>>(x, M, W_sd, b_sd, W_ds, b_ds, W_l1, b_l1, P);

    edge_kernel<<<(E + 3) / 4, THREADS, 0, stream>>>(P, src, dst, cnts, W_l2, b_l2,
                                                     h_in, h_out, indeg, outdeg, E);

    dim3 g4((M + BM - 1) / BM, 1);
    gemm_gate<<<g4, THREADS, 0, stream>>>(h_in, h_out, indeg, outdeg, M, W_g1, b_g1, G);

    finalize<<<(M + 3) / 4, THREADS, 0, stream>>>(G, W_g2, b_g2, h_in, h_out,
                                                  indeg, outdeg, x, (float*)d_out, M);
}

// Round 2
// 636.783 us; speedup vs baseline: 1.7229x; 1.7229x over previous
//
#include <hip/hip_runtime.h>
#include <math.h>

#define THREADS 256
#define BM 64
#define BN 128
#define BK 32
#define APAD 36

// ---------------------------------------------------------------------------
// K1: P[n, 0:512] = x[n] @ [W_sd | W_ds | W_l1_top | W_l1_bot] + bias
//     groups: p_sd (cols 0..127), p_ds (128..255), a=x@W_l1_top+b_l1 (256..383),
//             bb=x@W_l1_bot (384..511)
// ---------------------------------------------------------------------------
__global__ __launch_bounds__(THREADS)
void gemm_node(const float* __restrict__ X, int M,
               const float* __restrict__ W_sd, const float* __restrict__ b_sd,
               const float* __restrict__ W_ds, const float* __restrict__ b_ds,
               const float* __restrict__ W_l1, const float* __restrict__ b_l1,
               float* __restrict__ P)
{
    __shared__ float As[BM][APAD];
    __shared__ float Bs[BK][BN];

    const int tid = threadIdx.x;
    const int m0  = blockIdx.x * BM;
    const int grp = blockIdx.y;

    const float* B;
    const float* bias;
    if (grp == 0)      { B = W_sd;               bias = b_sd; }
    else if (grp == 1) { B = W_ds;               bias = b_ds; }
    else if (grp == 2) { B = W_l1;               bias = b_l1; }
    else               { B = W_l1 + 128 * 128;   bias = nullptr; }

    const int ty = tid >> 4;
    const int tx = tid & 15;

    float acc[4][8];
#pragma unroll
    for (int i = 0; i < 4; ++i)
#pragma unroll
        for (int j = 0; j < 8; ++j) acc[i][j] = 0.f;

    const int lrow = tid >> 3;
    const int lc4  = tid & 7;

    for (int k0 = 0; k0 < 128; k0 += BK) {
#pragma unroll
        for (int p = 0; p < 2; ++p) {
            int r  = lrow + p * 32;
            int gr = m0 + r; if (gr >= M) gr = M - 1;
            const float4 v = *(const float4*)(X + (size_t)gr * 128 + k0 + lc4 * 4);
            *(float4*)(&As[r][lc4 * 4]) = v;
        }
#pragma unroll
        for (int i = 0; i < 4; ++i) {
            int idx = tid + i * 256;
            int kr  = idx >> 5;
            int c4  = idx & 31;
            const float4 v = *(const float4*)(B + (size_t)(k0 + kr) * 128 + c4 * 4);
            *(float4*)(&Bs[kr][c4 * 4]) = v;
        }
        __syncthreads();

#pragma unroll
        for (int k = 0; k < BK; ++k) {
            float a[4];
#pragma unroll
            for (int i = 0; i < 4; ++i) a[i] = As[ty * 4 + i][k];
            const float4 b0 = *(const float4*)(&Bs[k][tx * 8]);
            const float4 b1 = *(const float4*)(&Bs[k][tx * 8 + 4]);
            const float bb[8] = {b0.x, b0.y, b0.z, b0.w, b1.x, b1.y, b1.z, b1.w};
#pragma unroll
            for (int i = 0; i < 4; ++i)
#pragma unroll
                for (int j = 0; j < 8; ++j)
                    acc[i][j] = fmaf(a[i], bb[j], acc[i][j]);
        }
        __syncthreads();
    }

#pragma unroll
    for (int i = 0; i < 4; ++i) {
        int gr = m0 + ty * 4 + i;
        if (gr < M) {
            float* dst = P + (size_t)gr * 512 + grp * 128 + tx * 8;
#pragma unroll
            for (int j = 0; j < 8; ++j) {
                float bv = bias ? bias[tx * 8 + j] : 0.f;
                dst[j] = acc[i][j] + bv;
            }
        }
    }
}

// ---------------------------------------------------------------------------
// K2: per-edge wave: w_e = sigmoid(sum relu(a[s]+bb[d])*W_l2 + b_l2) * cnt
//     + integer degree counting for CSR. No fat atomics.
// ---------------------------------------------------------------------------
__global__ __launch_bounds__(THREADS)
void edge_lcs(const float* __restrict__ P,
              const int* __restrict__ src, const int* __restrict__ dst,
              const float* __restrict__ counts,
              const float* __restrict__ W_l2, const float* __restrict__ b_l2,
              float* __restrict__ w_e,
              int* __restrict__ cnt_in, int* __restrict__ cnt_out, int E)
{
    const int lane = threadIdx.x & 63;
    const int wid  = threadIdx.x >> 6;
    const int e    = blockIdx.x * 4 + wid;
    if (e >= E) return;

    const int   s = src[e];
    const int   d = dst[e];
    const float c = counts[e];

    const float2* Ps = (const float2*)(P + (size_t)s * 512);
    const float2* Pd = (const float2*)(P + (size_t)d * 512);

    const float2 av = Ps[128 + lane];   // 'a'  cols 256..383
    const float2 bv = Pd[192 + lane];   // 'bb' cols 384..511
    const float  t0 = fmaxf(av.x + bv.x, 0.f);
    const float  t1 = fmaxf(av.y + bv.y, 0.f);
    const float2 w2 = *(const float2*)(W_l2 + 2 * lane);
    float part = t0 * w2.x + t1 * w2.y;
#pragma unroll
    for (int off = 32; off; off >>= 1) part += __shfl_xor(part, off);

    if (lane == 0) {
        const float lcs = 1.f / (1.f + expf(-(part + b_l2[0])));
        w_e[e] = lcs * c;
        atomicAdd(cnt_in + d, 1);
        atomicAdd(cnt_out + s, 1);
    }
}

// ---------------------------------------------------------------------------
// K3: exclusive scan of cnt -> off (two arrays, one block each; M <= 1024*chunk)
// ---------------------------------------------------------------------------
__global__ __launch_bounds__(1024)
void scan2(const int* __restrict__ cnt_in, int* __restrict__ off_in,
           const int* __restrict__ cnt_out, int* __restrict__ off_out, int M)
{
    const int* cnt = blockIdx.x ? cnt_out : cnt_in;
    int*       off = blockIdx.x ? off_out : off_in;

    __shared__ int sums[1024];
    const int t     = threadIdx.x;
    const int chunk = (M + 1023) >> 10;
    const int lo    = t * chunk;
    const int hi    = (lo + chunk < M) ? lo + chunk : M;

    int s = 0;
    for (int i = lo; i < hi; ++i) s += cnt[i];
    sums[t] = s;
    __syncthreads();

    for (int o = 1; o < 1024; o <<= 1) {
        int v = (t >= o) ? sums[t - o] : 0;
        __syncthreads();
        sums[t] += v;
        __syncthreads();
    }

    int run = (t > 0) ? sums[t - 1] : 0;
    for (int i = lo; i < hi; ++i) { off[i] = run; run += cnt[i]; }
}

// ---------------------------------------------------------------------------
// K4: fill CSR edge lists (cur_* zeroed beforehand; becomes per-node count)
// ---------------------------------------------------------------------------
__global__ __launch_bounds__(THREADS)
void fill_csr(const int* __restrict__ src, const int* __restrict__ dst,
              const int* __restrict__ off_in, const int* __restrict__ off_out,
              int* __restrict__ cur_in, int* __restrict__ cur_out,
              int* __restrict__ eidx_in, int* __restrict__ eidx_out, int E)
{
    const int e = blockIdx.x * THREADS + threadIdx.x;
    if (e >= E) return;
    const int d = dst[e];
    const int r1 = atomicAdd(cur_in + d, 1);
    eidx_in[off_in[d] + r1] = e;
    const int s = src[e];
    const int r2 = atomicAdd(cur_out + s, 1);
    eidx_out[off_out[s] + r2] = e;
}

// ---------------------------------------------------------------------------
// K5: gather-aggregate. One wave per (node, dir). Writes degree-normalized
//     h_in into P cols 256..383, h_out into P cols 384..511 (a/bb are dead).
// ---------------------------------------------------------------------------
__global__ __launch_bounds__(THREADS)
void node_agg(float* __restrict__ P,
              const int* __restrict__ src, const int* __restrict__ dst,
              const float* __restrict__ counts, const float* __restrict__ w_e,
              const int* __restrict__ off_in,  const int* __restrict__ n_in,
              const int* __restrict__ eidx_in,
              const int* __restrict__ off_out, const int* __restrict__ n_out,
              const int* __restrict__ eidx_out, int M)
{
    const int lane = threadIdx.x & 63;
    const int wid  = threadIdx.x >> 6;
    const int task = blockIdx.x * 4 + wid;
    if (task >= 2 * M) return;
    const int v   = task >> 1;
    const int dir = task & 1;           // 0: in (gather p_sd[src]), 1: out (gather p_ds[dst])

    const int  base  = dir ? off_out[v] : off_in[v];
    const int  n     = dir ? n_out[v]   : n_in[v];
    const int* eidx  = dir ? eidx_out   : eidx_in;
    const int* other = dir ? dst        : src;
    const int  cofs  = dir ? 64 : 0;    // float2 offset of p_ds / p_sd

    float ax = 0.f, ay = 0.f, deg = 0.f;
    for (int j = 0; j < n; ++j) {
        const int   e = eidx[base + j];
        const int   u = other[e];
        const float w = w_e[e];
        deg += counts[e];
        const float2 pv = ((const float2*)(P + (size_t)u * 512))[cofs + lane];
        ax = fmaf(pv.x, w, ax);
        ay = fmaf(pv.y, w, ay);
    }
    const float r = 1.f / fmaxf(deg, 1.f);
    float2 o; o.x = ax * r; o.y = ay * r;
    ((float2*)(P + (size_t)v * 512))[(dir ? 192 : 128) + lane] = o;
}

// ---------------------------------------------------------------------------
// K6: G = relu([h_in_n | h_out_n] @ W_g1 + b_g1); A row = P+v*512+256 (contig
//     256 floats), G written to P+v*512 (p_sd/p_ds dead).
// ---------------------------------------------------------------------------
__global__ __launch_bounds__(THREADS)
void gemm_gate(float* __restrict__ P, int M,
               const float* __restrict__ W_g1, const float* __restrict__ b_g1)
{
    __shared__ float As[BM][APAD];
    __shared__ float Bs[BK][BN];

    const int tid = threadIdx.x;
    const int m0  = blockIdx.x * BM;
    const int ty  = tid >> 4;
    const int tx  = tid & 15;

    float acc[4][8];
#pragma unroll
    for (int i = 0; i < 4; ++i)
#pragma unroll
        for (int j = 0; j < 8; ++j) acc[i][j] = 0.f;

    const int lrow = tid >> 3;
    const int lc4  = tid & 7;

    for (int k0 = 0; k0 < 256; k0 += BK) {
#pragma unroll
        for (int p = 0; p < 2; ++p) {
            int r  = lrow + p * 32;
            int gr = m0 + r; if (gr >= M) gr = M - 1;
            const float4 v = *(const float4*)(P + (size_t)gr * 512 + 256 + k0 + lc4 * 4);
            *(float4*)(&As[r][lc4 * 4]) = v;
        }
#pragma unroll
        for (int i = 0; i < 4; ++i) {
            int idx = tid + i * 256;
            int kr  = idx >> 5;
            int c4  = idx & 31;
            const float4 v = *(const float4*)(W_g1 + (size_t)(k0 + kr) * 128 + c4 * 4);
            *(float4*)(&Bs[kr][c4 * 4]) = v;
        }
        __syncthreads();

#pragma unroll
        for (int k = 0; k < BK; ++k) {
            float a[4];
#pragma unroll
            for (int i = 0; i < 4; ++i) a[i] = As[ty * 4 + i][k];
            const float4 b0 = *(const float4*)(&Bs[k][tx * 8]);
            const float4 b1 = *(const float4*)(&Bs[k][tx * 8 + 4]);
            const float bb[8] = {b0.x, b0.y, b0.z, b0.w, b1.x, b1.y, b1.z, b1.w};
#pragma unroll
            for (int i = 0; i < 4; ++i)
#pragma unroll
                for (int j = 0; j < 8; ++j)
                    acc[i][j] = fmaf(a[i], bb[j], acc[i][j]);
        }
        __syncthreads();
    }

#pragma unroll
    for (int i = 0; i < 4; ++i) {
        int gr = m0 + ty * 4 + i;
        if (gr < M) {
            float* dst = P + (size_t)gr * 512 + tx * 8;
#pragma unroll
            for (int j = 0; j < 8; ++j)
                dst[j] = fmaxf(acc[i][j] + b_g1[tx * 8 + j], 0.f);
        }
    }
}

// ---------------------------------------------------------------------------
// K7: gate = sigmoid(G[v]·W_g2 + b_g2); out = gate*h_in_n + (1-gate)*h_out_n + x
// ---------------------------------------------------------------------------
__global__ __launch_bounds__(THREADS)
void finalize(const float* __restrict__ P,
              const float* __restrict__ W_g2, const float* __restrict__ b_g2,
              const float* __restrict__ x, float* __restrict__ out, int M)
{
    const int lane = threadIdx.x & 63;
    const int wid  = threadIdx.x >> 6;
    const int v    = blockIdx.x * 4 + wid;
    if (v >= M) return;

    const float2* Pv = (const float2*)(P + (size_t)v * 512);

    const float2 g2 = Pv[lane];                 // G cols 0..127
    const float2 w2 = *(const float2*)(W_g2 + 2 * lane);
    float part = g2.x * w2.x + g2.y * w2.y;
#pragma unroll
    for (int off = 32; off; off >>= 1) part += __shfl_xor(part, off);
    const float gate = 1.f / (1.f + expf(-(part + b_g2[0])));

    const float2 hi = Pv[128 + lane];           // h_in_norm
    const float2 ho = Pv[192 + lane];           // h_out_norm
    const float2 xv = *(const float2*)(x + (size_t)v * 128 + 2 * lane);

    float2 o;
    o.x = gate * hi.x + (1.f - gate) * ho.x + xv.x;
    o.y = gate * hi.y + (1.f - gate) * ho.y + xv.y;
    *(float2*)(out + (size_t)v * 128 + 2 * lane) = o;
}

// ---------------------------------------------------------------------------
extern "C" void kernel_launch(void* const* d_in, const int* in_sizes, int n_in,
                              void* d_out, int out_size, void* d_ws, size_t ws_size,
                              hipStream_t stream)
{
    const float* x     = (const float*)d_in[0];
    const int*   src   = (const int*)  d_in[1];
    const int*   dst   = (const int*)  d_in[2];
    const float* cnts  = (const float*)d_in[3];
    const float* W_sd  = (const float*)d_in[4];
    const float* b_sd  = (const float*)d_in[5];
    const float* W_ds  = (const float*)d_in[6];
    const float* b_ds  = (const float*)d_in[7];
    const float* W_l1  = (const float*)d_in[8];
    const float* b_l1  = (const float*)d_in[9];
    const float* W_l2  = (const float*)d_in[10];
    const float* b_l2  = (const float*)d_in[11];
    const float* W_g1  = (const float*)d_in[12];
    const float* b_g1  = (const float*)d_in[13];
    const float* W_g2  = (const float*)d_in[14];
    const float* b_g2  = (const float*)d_in[15];

    const int M = in_sizes[0] / 128;   // nodes
    const int E = in_sizes[1];         // unique edges

    // workspace layout:
    //   P        : M*512 floats  (p_sd|p_ds|a|bb -> later p_sd|p_ds|h_in|h_out -> G|..)
    //   cnt_in   : M ints   (also reused as fill cursor / final per-node count)
    //   cnt_out  : M ints
    //   off_in   : M ints
    //   off_out  : M ints
    //   eidx_in  : E ints
    //   eidx_out : E ints
    //   w_e      : E floats
    float* P        = (float*)d_ws;
    int*   cnt_in   = (int*)(P + (size_t)M * 512);
    int*   cnt_out  = cnt_in + M;
    int*   off_in   = cnt_out + M;
    int*   off_out  = off_in + M;
    int*   eidx_in  = off_out + M;
    int*   eidx_out = eidx_in + E;
    float* w_e      = (float*)(eidx_out + E);

    // zero degree counters (cnt_in|cnt_out contiguous)
    hipMemsetAsync(cnt_in, 0, 2 * (size_t)M * sizeof(int), stream);

    dim3 g1((M + BM - 1) / BM, 4);
    gemm_node<<<g1, THREADS, 0, stream>>>(x, M, W_sd, b_sd, W_ds, b_ds, W_l1, b_l1, P);

    edge_lcs<<<(E + 3) / 4, THREADS, 0, stream>>>(P, src, dst, cnts, W_l2, b_l2,
                                                  w_e, cnt_in, cnt_out, E);

    scan2<<<2, 1024, 0, stream>>>(cnt_in, off_in, cnt_out, off_out, M);

    // re-zero counters to use as fill cursors
    hipMemsetAsync(cnt_in, 0, 2 * (size_t)M * sizeof(int), stream);

    fill_csr<<<(E + THREADS - 1) / THREADS, THREADS, 0, stream>>>(
        src, dst, off_in, off_out, cnt_in, cnt_out, eidx_in, eidx_out, E);

    node_agg<<<(2 * M + 3) / 4, THREADS, 0, stream>>>(
        P, src, dst, cnts, w_e, off_in, cnt_in, eidx_in, off_out, cnt_out, eidx_out, M);

    gemm_gate<<<(M + BM - 1) / BM, THREADS, 0, stream>>>(P, M, W_g1, b_g1);

    finalize<<<(M + 3) / 4, THREADS, 0, stream>>>(P, W_g2, b_g2, x, (float*)d_out, M);
}

// Round 4
// 517.585 us; speedup vs baseline: 2.1196x; 1.2303x over previous
//
#include <hip/hip_runtime.h>
#include <math.h>

typedef unsigned int uint;

#define THREADS 256
#define BM 64
#define BN 128
#define BK 32
#define APAD 36

// ---- bf16 helpers (storage-only; all math in fp32) ------------------------
__device__ __forceinline__ float blo(uint u) { return __uint_as_float(u << 16); }
__device__ __forceinline__ float bhi(uint u) { return __uint_as_float(u & 0xffff0000u); }
__device__ __forceinline__ uint  bf16r(float x) {           // RTNE
    uint u = __float_as_uint(x);
    return (u + 0x7fffu + ((u >> 16) & 1u)) >> 16;
}
__device__ __forceinline__ uint packbf(float lo, float hi) {
    return bf16r(lo) | (bf16r(hi) << 16);
}

// ---------------------------------------------------------------------------
// K1: P[n, 0:512] (bf16) = x[n] @ [W_sd | W_ds | W_l1_top | W_l1_bot] + bias
//     elems: p_sd 0..127 | p_ds 128..255 | a(+b_l1) 256..383 | bb 384..511
// ---------------------------------------------------------------------------
__global__ __launch_bounds__(THREADS)
void gemm_node(const float* __restrict__ X, int M,
               const float* __restrict__ W_sd, const float* __restrict__ b_sd,
               const float* __restrict__ W_ds, const float* __restrict__ b_ds,
               const float* __restrict__ W_l1, const float* __restrict__ b_l1,
               ushort* __restrict__ Pb)
{
    __shared__ float As[BM][APAD];
    __shared__ float Bs[BK][BN];

    const int tid = threadIdx.x;
    const int m0  = blockIdx.x * BM;
    const int grp = blockIdx.y;

    const float* B;
    const float* bias;
    if (grp == 0)      { B = W_sd;               bias = b_sd; }
    else if (grp == 1) { B = W_ds;               bias = b_ds; }
    else if (grp == 2) { B = W_l1;               bias = b_l1; }
    else               { B = W_l1 + 128 * 128;   bias = nullptr; }

    const int ty = tid >> 4;
    const int tx = tid & 15;

    float acc[4][8];
#pragma unroll
    for (int i = 0; i < 4; ++i)
#pragma unroll
        for (int j = 0; j < 8; ++j) acc[i][j] = 0.f;

    const int lrow = tid >> 3;
    const int lc4  = tid & 7;

    for (int k0 = 0; k0 < 128; k0 += BK) {
#pragma unroll
        for (int p = 0; p < 2; ++p) {
            int r  = lrow + p * 32;
            int gr = m0 + r; if (gr >= M) gr = M - 1;
            const float4 v = *(const float4*)(X + (size_t)gr * 128 + k0 + lc4 * 4);
            *(float4*)(&As[r][lc4 * 4]) = v;
        }
#pragma unroll
        for (int i = 0; i < 4; ++i) {
            int idx = tid + i * 256;
            int kr  = idx >> 5;
            int c4  = idx & 31;
            const float4 v = *(const float4*)(B + (size_t)(k0 + kr) * 128 + c4 * 4);
            *(float4*)(&Bs[kr][c4 * 4]) = v;
        }
        __syncthreads();

#pragma unroll
        for (int k = 0; k < BK; ++k) {
            float a[4];
#pragma unroll
            for (int i = 0; i < 4; ++i) a[i] = As[ty * 4 + i][k];
            const float4 b0 = *(const float4*)(&Bs[k][tx * 8]);
            const float4 b1 = *(const float4*)(&Bs[k][tx * 8 + 4]);
            const float bb[8] = {b0.x, b0.y, b0.z, b0.w, b1.x, b1.y, b1.z, b1.w};
#pragma unroll
            for (int i = 0; i < 4; ++i)
#pragma unroll
                for (int j = 0; j < 8; ++j)
                    acc[i][j] = fmaf(a[i], bb[j], acc[i][j]);
        }
        __syncthreads();
    }

#pragma unroll
    for (int i = 0; i < 4; ++i) {
        int gr = m0 + ty * 4 + i;
        if (gr < M) {
            float v[8];
#pragma unroll
            for (int j = 0; j < 8; ++j) {
                float bv = bias ? bias[tx * 8 + j] : 0.f;
                v[j] = acc[i][j] + bv;
            }
            uint4 o;
            o.x = packbf(v[0], v[1]); o.y = packbf(v[2], v[3]);
            o.z = packbf(v[4], v[5]); o.w = packbf(v[6], v[7]);
            // group stride = 128 bf16 elems = 64 uints  (R3 bug: was grp*32)
            *(uint4*)((uint*)Pb + (size_t)gr * 256 + grp * 64 + tx * 4) = o;
        }
    }
}

// ---------------------------------------------------------------------------
// K2: 2 edges per wave (32 lanes each): w_e = sigmoid(relu(a[s]+bb[d])·W_l2
//     + b_l2)*cnt ; count degrees (int for CSR, float weighted for norm).
// ---------------------------------------------------------------------------
__global__ __launch_bounds__(THREADS)
void edge_lcs(const ushort* __restrict__ Pb,
              const int* __restrict__ src, const int* __restrict__ dst,
              const float* __restrict__ counts,
              const float* __restrict__ W_l2, const float* __restrict__ b_l2,
              float* __restrict__ w_e,
              int* __restrict__ cnt_in, int* __restrict__ cnt_out,
              float* __restrict__ deg_in, float* __restrict__ deg_out, int E)
{
    const int lane = threadIdx.x & 63;
    const int wid  = threadIdx.x >> 6;
    const int hl   = lane & 31;
    const int sel  = lane >> 5;
    int e = (blockIdx.x * 4 + wid) * 2 + sel;
    const bool valid = (e < E);
    if (e >= E) e = E - 1;

    const int   s = src[e];
    const int   d = dst[e];
    const float c = counts[e];

    const uint* rs = (const uint*)Pb + (size_t)s * 256;   // row as uints (2 bf16 each)
    const uint* rd = (const uint*)Pb + (size_t)d * 256;

    const uint2 av = ((const uint2*)(rs + 128))[hl];      // a  : elems 256..383
    const uint2 bv = ((const uint2*)(rd + 192))[hl];      // bb : elems 384..511

    const float t0 = fmaxf(blo(av.x) + blo(bv.x), 0.f);
    const float t1 = fmaxf(bhi(av.x) + bhi(bv.x), 0.f);
    const float t2 = fmaxf(blo(av.y) + blo(bv.y), 0.f);
    const float t3 = fmaxf(bhi(av.y) + bhi(bv.y), 0.f);

    const float4 w2 = *(const float4*)(W_l2 + hl * 4);
    float part = t0 * w2.x + t1 * w2.y + t2 * w2.z + t3 * w2.w;
#pragma unroll
    for (int off = 16; off; off >>= 1) part += __shfl_xor(part, off);

    if (hl == 0 && valid) {
        const float lcs = 1.f / (1.f + expf(-(part + b_l2[0])));
        w_e[e] = lcs * c;
        atomicAdd(cnt_in + d, 1);
        atomicAdd(cnt_out + s, 1);
        atomicAdd(deg_in + d, c);
        atomicAdd(deg_out + s, c);
    }
}

// ---------------------------------------------------------------------------
// K3: exclusive scan of cnt -> off (one block per array)
// ---------------------------------------------------------------------------
__global__ __launch_bounds__(1024)
void scan2(const int* __restrict__ cnt_in, int* __restrict__ off_in,
           const int* __restrict__ cnt_out, int* __restrict__ off_out, int M)
{
    const int* cnt = blockIdx.x ? cnt_out : cnt_in;
    int*       off = blockIdx.x ? off_out : off_in;

    __shared__ int sums[1024];
    const int t     = threadIdx.x;
    const int chunk = (M + 1023) >> 10;
    const int lo    = t * chunk;
    const int hi    = (lo + chunk < M) ? lo + chunk : M;

    int s = 0;
    for (int i = lo; i < hi; ++i) s += cnt[i];
    sums[t] = s;
    __syncthreads();

    for (int o = 1; o < 1024; o <<= 1) {
        int v = (t >= o) ? sums[t - o] : 0;
        __syncthreads();
        sums[t] += v;
        __syncthreads();
    }

    int run = (t > 0) ? sums[t - 1] : 0;
    for (int i = lo; i < hi; ++i) { off[i] = run; run += cnt[i]; }
}

// ---------------------------------------------------------------------------
// K4: fill value-reordered CSR: per slot store (u as int bits, w) as float2
// ---------------------------------------------------------------------------
__global__ __launch_bounds__(THREADS)
void fill_csr(const int* __restrict__ src, const int* __restrict__ dst,
              const float* __restrict__ w_e,
              const int* __restrict__ off_in, const int* __restrict__ off_out,
              int* __restrict__ cur_in, int* __restrict__ cur_out,
              float2* __restrict__ uw_in, float2* __restrict__ uw_out, int E)
{
    const int e = blockIdx.x * THREADS + threadIdx.x;
    if (e >= E) return;
    const int   s = src[e];
    const int   d = dst[e];
    const float w = w_e[e];
    const int r1 = atomicAdd(cur_in + d, 1);
    uw_in[off_in[d] + r1] = make_float2(__int_as_float(s), w);
    const int r2 = atomicAdd(cur_out + s, 1);
    uw_out[off_out[s] + r2] = make_float2(__int_as_float(d), w);
}

// ---------------------------------------------------------------------------
// K5: gather-aggregate, 1 wave per (node,dir), 2 edges in flight (32-lane
//     halves). Writes degree-normalized h_in -> elems 256..383, h_out ->
//     384..511 (bf16, a/bb dead).
// ---------------------------------------------------------------------------
__global__ __launch_bounds__(THREADS)
void node_agg(ushort* __restrict__ Pb,
              const float2* __restrict__ uw_in, const float2* __restrict__ uw_out,
              const int* __restrict__ off_in,  const int* __restrict__ cnt_in,
              const int* __restrict__ off_out, const int* __restrict__ cnt_out,
              const float* __restrict__ deg_in, const float* __restrict__ deg_out,
              int M)
{
    const int lane = threadIdx.x & 63;
    const int wid  = threadIdx.x >> 6;
    const int task = blockIdx.x * 4 + wid;
    if (task >= 2 * M) return;
    const int v   = task >> 1;
    const int dir = task & 1;    // 0: in (gather p_sd[src]), 1: out (gather p_ds[dst])

    const int           base = dir ? off_out[v] : off_in[v];
    const int           n    = dir ? cnt_out[v] : cnt_in[v];
    const float2* __restrict__ uw = (dir ? uw_out : uw_in) + base;
    const int           uofs = dir ? 64 : 0;      // uint offset of p_ds / p_sd
    const int hl  = lane & 31;
    const int sel = lane >> 5;

    float a0 = 0.f, a1 = 0.f, a2 = 0.f, a3 = 0.f;
    for (int j = sel; j < n; j += 2) {
        const float2 p = uw[j];
        const int    u = __float_as_int(p.x);
        const float  w = p.y;
        const uint2 pv = ((const uint2*)((const uint*)Pb + (size_t)u * 256 + uofs))[hl];
        a0 = fmaf(blo(pv.x), w, a0);
        a1 = fmaf(bhi(pv.x), w, a1);
        a2 = fmaf(blo(pv.y), w, a2);
        a3 = fmaf(bhi(pv.y), w, a3);
    }
    a0 += __shfl_xor(a0, 32);
    a1 += __shfl_xor(a1, 32);
    a2 += __shfl_xor(a2, 32);
    a3 += __shfl_xor(a3, 32);

    if (sel == 0) {
        const float dg = dir ? deg_out[v] : deg_in[v];
        const float r  = 1.f / fmaxf(dg, 1.f);
        uint2 o;
        o.x = packbf(a0 * r, a1 * r);
        o.y = packbf(a2 * r, a3 * r);
        ((uint2*)((uint*)Pb + (size_t)v * 256 + (dir ? 192 : 128)))[hl] = o;
    }
}

// ---------------------------------------------------------------------------
// K6: G = relu([h_in_n | h_out_n] @ W_g1 + b_g1)  (A bf16 from P elems
//     256..511, K=256); G (bf16) -> P elems 0..127 (p_sd/p_ds dead)
// ---------------------------------------------------------------------------
__global__ __launch_bounds__(THREADS)
void gemm_gate(ushort* __restrict__ Pb, int M,
               const float* __restrict__ W_g1, const float* __restrict__ b_g1)
{
    __shared__ float As[BM][APAD];
    __shared__ float Bs[BK][BN];

    const int tid = threadIdx.x;
    const int m0  = blockIdx.x * BM;
    const int ty  = tid >> 4;
    const int tx  = tid & 15;

    float acc[4][8];
#pragma unroll
    for (int i = 0; i < 4; ++i)
#pragma unroll
        for (int j = 0; j < 8; ++j) acc[i][j] = 0.f;

    const int lrow = tid >> 3;
    const int lc4  = tid & 7;

    for (int k0 = 0; k0 < 256; k0 += BK) {
#pragma unroll
        for (int p = 0; p < 2; ++p) {
            int r  = lrow + p * 32;
            int gr = m0 + r; if (gr >= M) gr = M - 1;
            const uint2 raw = *(const uint2*)((const uint*)Pb + (size_t)gr * 256 + 128 + k0 / 2 + lc4 * 2);
            float4 v;
            v.x = blo(raw.x); v.y = bhi(raw.x); v.z = blo(raw.y); v.w = bhi(raw.y);
            *(float4*)(&As[r][lc4 * 4]) = v;
        }
#pragma unroll
        for (int i = 0; i < 4; ++i) {
            int idx = tid + i * 256;
            int kr  = idx >> 5;
            int c4  = idx & 31;
            const float4 v = *(const float4*)(W_g1 + (size_t)(k0 + kr) * 128 + c4 * 4);
            *(float4*)(&Bs[kr][c4 * 4]) = v;
        }
        __syncthreads();

#pragma unroll
        for (int k = 0; k < BK; ++k) {
            float a[4];
#pragma unroll
            for (int i = 0; i < 4; ++i) a[i] = As[ty * 4 + i][k];
            const float4 b0 = *(const float4*)(&Bs[k][tx * 8]);
            const float4 b1 = *(const float4*)(&Bs[k][tx * 8 + 4]);
            const float bb[8] = {b0.x, b0.y, b0.z, b0.w, b1.x, b1.y, b1.z, b1.w};
#pragma unroll
            for (int i = 0; i < 4; ++i)
#pragma unroll
                for (int j = 0; j < 8; ++j)
                    acc[i][j] = fmaf(a[i], bb[j], acc[i][j]);
        }
        __syncthreads();
    }

#pragma unroll
    for (int i = 0; i < 4; ++i) {
        int gr = m0 + ty * 4 + i;
        if (gr < M) {
            float v[8];
#pragma unroll
            for (int j = 0; j < 8; ++j)
                v[j] = fmaxf(acc[i][j] + b_g1[tx * 8 + j], 0.f);
            uint4 o;
            o.x = packbf(v[0], v[1]); o.y = packbf(v[2], v[3]);
            o.z = packbf(v[4], v[5]); o.w = packbf(v[6], v[7]);
            *(uint4*)((uint*)Pb + (size_t)gr * 256 + tx * 4) = o;
        }
    }
}

// ---------------------------------------------------------------------------
// K7: gate = sigmoid(G[v]·W_g2 + b_g2); out = gate*h_in_n + (1-gate)*h_out_n + x
// ---------------------------------------------------------------------------
__global__ __launch_bounds__(THREADS)
void finalize(const ushort* __restrict__ Pb,
              const float* __restrict__ W_g2, const float* __restrict__ b_g2,
              const float* __restrict__ x, float* __restrict__ out, int M)
{
    const int lane = threadIdx.x & 63;
    const int wid  = threadIdx.x >> 6;
    const int v    = blockIdx.x * 4 + wid;
    if (v >= M) return;

    const uint* row = (const uint*)Pb + (size_t)v * 256;

    const uint  gv = row[lane];                      // G elems 2*lane, 2*lane+1
    const float2 w2 = *(const float2*)(W_g2 + 2 * lane);
    float part = blo(gv) * w2.x + bhi(gv) * w2.y;
#pragma unroll
    for (int off = 32; off; off >>= 1) part += __shfl_xor(part, off);
    const float gate = 1.f / (1.f + expf(-(part + b_g2[0])));

    const uint hiv = row[128 + lane];                // h_in_norm
    const uint hov = row[192 + lane];                // h_out_norm
    const float2 xv = *(const float2*)(x + (size_t)v * 128 + 2 * lane);

    float2 o;
    o.x = gate * blo(hiv) + (1.f - gate) * blo(hov) + xv.x;
    o.y = gate * bhi(hiv) + (1.f - gate) * bhi(hov) + xv.y;
    *(float2*)(out + (size_t)v * 128 + 2 * lane) = o;
}

// ---------------------------------------------------------------------------
extern "C" void kernel_launch(void* const* d_in, const int* in_sizes, int n_in,
                              void* d_out, int out_size, void* d_ws, size_t ws_size,
                              hipStream_t stream)
{
    const float* x     = (const float*)d_in[0];
    const int*   src   = (const int*)  d_in[1];
    const int*   dst   = (const int*)  d_in[2];
    const float* cnts  = (const float*)d_in[3];
    const float* W_sd  = (const float*)d_in[4];
    const float* b_sd  = (const float*)d_in[5];
    const float* W_ds  = (const float*)d_in[6];
    const float* b_ds  = (const float*)d_in[7];
    const float* W_l1  = (const float*)d_in[8];
    const float* b_l1  = (const float*)d_in[9];
    const float* W_l2  = (const float*)d_in[10];
    const float* b_l2  = (const float*)d_in[11];
    const float* W_g1  = (const float*)d_in[12];
    const float* b_g1  = (const float*)d_in[13];
    const float* W_g2  = (const float*)d_in[14];
    const float* b_g2  = (const float*)d_in[15];

    const int M = in_sizes[0] / 128;
    const int E = in_sizes[1];

    // workspace (bytes, all offsets 8B-aligned):
    //   Pb      : M*512 bf16 (1 KB/row)
    //   cnt_in, cnt_out, cur_in, cur_out : int[M]   (zeroed)
    //   deg_in, deg_out                  : float[M] (zeroed)
    //   off_in, off_out                  : int[M]
    //   uw_in, uw_out                    : float2[E]
    //   w_e                              : float[E]
    ushort* Pb      = (ushort*)d_ws;
    int*    cnt_in  = (int*)(Pb + (size_t)M * 512);
    int*    cnt_out = cnt_in + M;
    int*    cur_in  = cnt_out + M;
    int*    cur_out = cur_in + M;
    float*  deg_in  = (float*)(cur_out + M);
    float*  deg_out = deg_in + M;
    int*    off_in  = (int*)(deg_out + M);
    int*    off_out = off_in + M;
    float2* uw_in   = (float2*)(off_out + M);
    float2* uw_out  = uw_in + E;
    float*  w_e     = (float*)(uw_out + E);

    // zero cnt_in..deg_out (6 contiguous arrays)
    hipMemsetAsync(cnt_in, 0, 6 * (size_t)M * sizeof(int), stream);

    dim3 g1((M + BM - 1) / BM, 4);
    gemm_node<<<g1, THREADS, 0, stream>>>(x, M, W_sd, b_sd, W_ds, b_ds, W_l1, b_l1, Pb);

    edge_lcs<<<(E + 7) / 8, THREADS, 0, stream>>>(Pb, src, dst, cnts, W_l2, b_l2,
                                                  w_e, cnt_in, cnt_out, deg_in, deg_out, E);

    scan2<<<2, 1024, 0, stream>>>(cnt_in, off_in, cnt_out, off_out, M);

    fill_csr<<<(E + THREADS - 1) / THREADS, THREADS, 0, stream>>>(
        src, dst, w_e, off_in, off_out, cur_in, cur_out, uw_in, uw_out, E);

    node_agg<<<(2 * M + 3) / 4, THREADS, 0, stream>>>(
        Pb, uw_in, uw_out, off_in, cnt_in, off_out, cnt_out, deg_in, deg_out, M);

    gemm_gate<<<(M + BM - 1) / BM, THREADS, 0, stream>>>(Pb, M, W_g1, b_g1);

    finalize<<<(M + 3) / 4, THREADS, 0, stream>>>(Pb, W_g2, b_g2, x, (float*)d_out, M);
}

// Round 5
// 466.206 us; speedup vs baseline: 2.3532x; 1.1102x over previous
//
#include <hip/hip_runtime.h>
#include <math.h>

typedef unsigned int uint;

#define THREADS 256
#define BM 64
#define BN 128
#define BK 32
#define APAD 36

// ---- bf16 helpers (storage-only; all math in fp32) ------------------------
__device__ __forceinline__ float blo(uint u) { return __uint_as_float(u << 16); }
__device__ __forceinline__ float bhi(uint u) { return __uint_as_float(u & 0xffff0000u); }
__device__ __forceinline__ uint  bf16r(float x) {           // RTNE
    uint u = __float_as_uint(x);
    return (u + 0x7fffu + ((u >> 16) & 1u)) >> 16;
}
__device__ __forceinline__ uint packbf(float lo, float hi) {
    return bf16r(lo) | (bf16r(hi) << 16);
}

// ---------------------------------------------------------------------------
// K1: P[n, 0:512] (bf16) = x[n] @ [W_sd | W_ds | W_l1_top | W_l1_bot] + bias
//     elems: p_sd 0..127 | p_ds 128..255 | a(+b_l1) 256..383 | bb 384..511
// ---------------------------------------------------------------------------
__global__ __launch_bounds__(THREADS)
void gemm_node(const float* __restrict__ X, int M,
               const float* __restrict__ W_sd, const float* __restrict__ b_sd,
               const float* __restrict__ W_ds, const float* __restrict__ b_ds,
               const float* __restrict__ W_l1, const float* __restrict__ b_l1,
               ushort* __restrict__ Pb)
{
    __shared__ float As[BM][APAD];
    __shared__ float Bs[BK][BN];

    const int tid = threadIdx.x;
    const int m0  = blockIdx.x * BM;
    const int grp = blockIdx.y;

    const float* B;
    const float* bias;
    if (grp == 0)      { B = W_sd;               bias = b_sd; }
    else if (grp == 1) { B = W_ds;               bias = b_ds; }
    else if (grp == 2) { B = W_l1;               bias = b_l1; }
    else               { B = W_l1 + 128 * 128;   bias = nullptr; }

    const int ty = tid >> 4;
    const int tx = tid & 15;

    float acc[4][8];
#pragma unroll
    for (int i = 0; i < 4; ++i)
#pragma unroll
        for (int j = 0; j < 8; ++j) acc[i][j] = 0.f;

    const int lrow = tid >> 3;
    const int lc4  = tid & 7;

    for (int k0 = 0; k0 < 128; k0 += BK) {
#pragma unroll
        for (int p = 0; p < 2; ++p) {
            int r  = lrow + p * 32;
            int gr = m0 + r; if (gr >= M) gr = M - 1;
            const float4 v = *(const float4*)(X + (size_t)gr * 128 + k0 + lc4 * 4);
            *(float4*)(&As[r][lc4 * 4]) = v;
        }
#pragma unroll
        for (int i = 0; i < 4; ++i) {
            int idx = tid + i * 256;
            int kr  = idx >> 5;
            int c4  = idx & 31;
            const float4 v = *(const float4*)(B + (size_t)(k0 + kr) * 128 + c4 * 4);
            *(float4*)(&Bs[kr][c4 * 4]) = v;
        }
        __syncthreads();

#pragma unroll
        for (int k = 0; k < BK; ++k) {
            float a[4];
#pragma unroll
            for (int i = 0; i < 4; ++i) a[i] = As[ty * 4 + i][k];
            const float4 b0 = *(const float4*)(&Bs[k][tx * 8]);
            const float4 b1 = *(const float4*)(&Bs[k][tx * 8 + 4]);
            const float bb[8] = {b0.x, b0.y, b0.z, b0.w, b1.x, b1.y, b1.z, b1.w};
#pragma unroll
            for (int i = 0; i < 4; ++i)
#pragma unroll
                for (int j = 0; j < 8; ++j)
                    acc[i][j] = fmaf(a[i], bb[j], acc[i][j]);
        }
        __syncthreads();
    }

#pragma unroll
    for (int i = 0; i < 4; ++i) {
        int gr = m0 + ty * 4 + i;
        if (gr < M) {
            float v[8];
#pragma unroll
            for (int j = 0; j < 8; ++j) {
                float bv = bias ? bias[tx * 8 + j] : 0.f;
                v[j] = acc[i][j] + bv;
            }
            uint4 o;
            o.x = packbf(v[0], v[1]); o.y = packbf(v[2], v[3]);
            o.z = packbf(v[4], v[5]); o.w = packbf(v[6], v[7]);
            *(uint4*)((uint*)Pb + (size_t)gr * 256 + grp * 64 + tx * 4) = o;
        }
    }
}

// ---------------------------------------------------------------------------
// K2: edge_count — 1 thread/edge, degree atomics only (no gathers)
// ---------------------------------------------------------------------------
__global__ __launch_bounds__(THREADS)
void edge_count(const int* __restrict__ src, const int* __restrict__ dst,
                const float* __restrict__ counts,
                int* __restrict__ cnt_in, int* __restrict__ cnt_out,
                float* __restrict__ deg_in, float* __restrict__ deg_out, int E)
{
    const int e = blockIdx.x * THREADS + threadIdx.x;
    if (e >= E) return;
    const int   s = src[e];
    const int   d = dst[e];
    const float c = counts[e];
    atomicAdd(cnt_in + d, 1);
    atomicAdd(cnt_out + s, 1);
    atomicAdd(deg_in + d, c);
    atomicAdd(deg_out + s, c);
}

// ---------------------------------------------------------------------------
// K3: exclusive scan of cnt -> off (one block per array)
// ---------------------------------------------------------------------------
__global__ __launch_bounds__(1024)
void scan2(const int* __restrict__ cnt_in, int* __restrict__ off_in,
           const int* __restrict__ cnt_out, int* __restrict__ off_out, int M)
{
    const int* cnt = blockIdx.x ? cnt_out : cnt_in;
    int*       off = blockIdx.x ? off_out : off_in;

    __shared__ int sums[1024];
    const int t     = threadIdx.x;
    const int chunk = (M + 1023) >> 10;
    const int lo    = t * chunk;
    const int hi    = (lo + chunk < M) ? lo + chunk : M;

    int s = 0;
    for (int i = lo; i < hi; ++i) s += cnt[i];
    sums[t] = s;
    __syncthreads();

    for (int o = 1; o < 1024; o <<= 1) {
        int v = (t >= o) ? sums[t - o] : 0;
        __syncthreads();
        sums[t] += v;
        __syncthreads();
    }

    int run = (t > 0) ? sums[t - 1] : 0;
    for (int i = lo; i < hi; ++i) { off[i] = run; run += cnt[i]; }
}

// ---------------------------------------------------------------------------
// K4: edge_lcs_fill — 4 edges/wave, 16 lanes/edge (uint4 = 8 bf16 per lane).
//     w = sigmoid(relu(a[s]+bb[d])·W_l2 + b_l2)*cnt; write (u,w) CSR slots.
// ---------------------------------------------------------------------------
__global__ __launch_bounds__(THREADS)
void edge_lcs_fill(const ushort* __restrict__ Pb,
                   const int* __restrict__ src, const int* __restrict__ dst,
                   const float* __restrict__ counts,
                   const float* __restrict__ W_l2, const float* __restrict__ b_l2,
                   const int* __restrict__ off_in, const int* __restrict__ off_out,
                   int* __restrict__ cur_in, int* __restrict__ cur_out,
                   float2* __restrict__ uw_in, float2* __restrict__ uw_out, int E)
{
    const int lane = threadIdx.x & 63;
    const int wid  = threadIdx.x >> 6;
    const int g    = lane >> 4;       // edge slot within wave (0..3)
    const int gl   = lane & 15;
    int e = (blockIdx.x * 4 + wid) * 4 + g;
    const bool valid = (e < E);
    if (!valid) e = E - 1;

    const int   s = src[e];
    const int   d = dst[e];
    const float c = counts[e];

    const uint* rs = (const uint*)Pb + (size_t)s * 256;
    const uint* rd = (const uint*)Pb + (size_t)d * 256;

    const uint4 av = ((const uint4*)(rs + 128))[gl];   // a  : elems 256..383
    const uint4 bv = ((const uint4*)(rd + 192))[gl];   // bb : elems 384..511

    const float4 wa = ((const float4*)W_l2)[gl * 2];
    const float4 wb = ((const float4*)W_l2)[gl * 2 + 1];

    float part =
        fmaxf(blo(av.x) + blo(bv.x), 0.f) * wa.x + fmaxf(bhi(av.x) + bhi(bv.x), 0.f) * wa.y +
        fmaxf(blo(av.y) + blo(bv.y), 0.f) * wa.z + fmaxf(bhi(av.y) + bhi(bv.y), 0.f) * wa.w +
        fmaxf(blo(av.z) + blo(bv.z), 0.f) * wb.x + fmaxf(bhi(av.z) + bhi(bv.z), 0.f) * wb.y +
        fmaxf(blo(av.w) + blo(bv.w), 0.f) * wb.z + fmaxf(bhi(av.w) + bhi(bv.w), 0.f) * wb.w;

    part += __shfl_xor(part, 1);
    part += __shfl_xor(part, 2);
    part += __shfl_xor(part, 4);
    part += __shfl_xor(part, 8);

    if (gl == 0 && valid) {
        const float lcs = 1.f / (1.f + expf(-(part + b_l2[0])));
        const float w   = lcs * c;
        const int r1 = atomicAdd(cur_in + d, 1);
        uw_in[off_in[d] + r1] = make_float2(__int_as_float(s), w);
        const int r2 = atomicAdd(cur_out + s, 1);
        uw_out[off_out[s] + r2] = make_float2(__int_as_float(d), w);
    }
}

// ---------------------------------------------------------------------------
// K5: node_agg — 1 wave per (node,dir), 4 edge-groups of 16 lanes (uint4 row
//     gather). Writes degree-normalized h_in -> elems 256..383, h_out ->
//     384..511 (bf16; a/bb dead).
// ---------------------------------------------------------------------------
__global__ __launch_bounds__(THREADS)
void node_agg(ushort* __restrict__ Pb,
              const float2* __restrict__ uw_in, const float2* __restrict__ uw_out,
              const int* __restrict__ off_in,  const int* __restrict__ cnt_in,
              const int* __restrict__ off_out, const int* __restrict__ cnt_out,
              const float* __restrict__ deg_in, const float* __restrict__ deg_out,
              int M)
{
    const int lane = threadIdx.x & 63;
    const int wid  = threadIdx.x >> 6;
    const int task = blockIdx.x * 4 + wid;
    if (task >= 2 * M) return;
    const int v   = task >> 1;
    const int dir = task & 1;    // 0: in (gather p_sd[src]), 1: out (gather p_ds[dst])

    const int           base = dir ? off_out[v] : off_in[v];
    const int           n    = dir ? cnt_out[v] : cnt_in[v];
    const float2* __restrict__ uw = (dir ? uw_out : uw_in) + base;
    const int           uofs = dir ? 64 : 0;      // uint offset of p_ds / p_sd
    const int g  = lane >> 4;     // edge group 0..3
    const int gl = lane & 15;     // 8 elems per lane

    float a0 = 0.f, a1 = 0.f, a2 = 0.f, a3 = 0.f;
    float a4 = 0.f, a5 = 0.f, a6 = 0.f, a7 = 0.f;
    for (int j = g; j < n; j += 4) {
        const float2 p = uw[j];
        const int    u = __float_as_int(p.x);
        const float  w = p.y;
        const uint4 pv = ((const uint4*)((const uint*)Pb + (size_t)u * 256 + uofs))[gl];
        a0 = fmaf(blo(pv.x), w, a0);
        a1 = fmaf(bhi(pv.x), w, a1);
        a2 = fmaf(blo(pv.y), w, a2);
        a3 = fmaf(bhi(pv.y), w, a3);
        a4 = fmaf(blo(pv.z), w, a4);
        a5 = fmaf(bhi(pv.z), w, a5);
        a6 = fmaf(blo(pv.w), w, a6);
        a7 = fmaf(bhi(pv.w), w, a7);
    }
    // combine the 4 edge-groups (lanes gl, gl+16, gl+32, gl+48)
#define RED2(a) a += __shfl_xor(a, 16); a += __shfl_xor(a, 32);
    RED2(a0) RED2(a1) RED2(a2) RED2(a3) RED2(a4) RED2(a5) RED2(a6) RED2(a7)
#undef RED2

    if (g == 0) {
        const float dg = dir ? deg_out[v] : deg_in[v];
        const float r  = 1.f / fmaxf(dg, 1.f);
        uint4 o;
        o.x = packbf(a0 * r, a1 * r);
        o.y = packbf(a2 * r, a3 * r);
        o.z = packbf(a4 * r, a5 * r);
        o.w = packbf(a6 * r, a7 * r);
        ((uint4*)((uint*)Pb + (size_t)v * 256 + (dir ? 192 : 128)))[gl] = o;
    }
}

// ---------------------------------------------------------------------------
// K6: G = relu([h_in_n | h_out_n] @ W_g1 + b_g1)  (A bf16 from P elems
//     256..511, K=256); G (bf16) -> P elems 0..127 (p_sd/p_ds dead)
// ---------------------------------------------------------------------------
__global__ __launch_bounds__(THREADS)
void gemm_gate(ushort* __restrict__ Pb, int M,
               const float* __restrict__ W_g1, const float* __restrict__ b_g1)
{
    __shared__ float As[BM][APAD];
    __shared__ float Bs[BK][BN];

    const int tid = threadIdx.x;
    const int m0  = blockIdx.x * BM;
    const int ty  = tid >> 4;
    const int tx  = tid & 15;

    float acc[4][8];
#pragma unroll
    for (int i = 0; i < 4; ++i)
#pragma unroll
        for (int j = 0; j < 8; ++j) acc[i][j] = 0.f;

    const int lrow = tid >> 3;
    const int lc4  = tid & 7;

    for (int k0 = 0; k0 < 256; k0 += BK) {
#pragma unroll
        for (int p = 0; p < 2; ++p) {
            int r  = lrow + p * 32;
            int gr = m0 + r; if (gr >= M) gr = M - 1;
            const uint2 raw = *(const uint2*)((const uint*)Pb + (size_t)gr * 256 + 128 + k0 / 2 + lc4 * 2);
            float4 v;
            v.x = blo(raw.x); v.y = bhi(raw.x); v.z = blo(raw.y); v.w = bhi(raw.y);
            *(float4*)(&As[r][lc4 * 4]) = v;
        }
#pragma unroll
        for (int i = 0; i < 4; ++i) {
            int idx = tid + i * 256;
            int kr  = idx >> 5;
            int c4  = idx & 31;
            const float4 v = *(const float4*)(W_g1 + (size_t)(k0 + kr) * 128 + c4 * 4);
            *(float4*)(&Bs[kr][c4 * 4]) = v;
        }
        __syncthreads();

#pragma unroll
        for (int k = 0; k < BK; ++k) {
            float a[4];
#pragma unroll
            for (int i = 0; i < 4; ++i) a[i] = As[ty * 4 + i][k];
            const float4 b0 = *(const float4*)(&Bs[k][tx * 8]);
            const float4 b1 = *(const float4*)(&Bs[k][tx * 8 + 4]);
            const float bb[8] = {b0.x, b0.y, b0.z, b0.w, b1.x, b1.y, b1.z, b1.w};
#pragma unroll
            for (int i = 0; i < 4; ++i)
#pragma unroll
                for (int j = 0; j < 8; ++j)
                    acc[i][j] = fmaf(a[i], bb[j], acc[i][j]);
        }
        __syncthreads();
    }

#pragma unroll
    for (int i = 0; i < 4; ++i) {
        int gr = m0 + ty * 4 + i;
        if (gr < M) {
            float v[8];
#pragma unroll
            for (int j = 0; j < 8; ++j)
                v[j] = fmaxf(acc[i][j] + b_g1[tx * 8 + j], 0.f);
            uint4 o;
            o.x = packbf(v[0], v[1]); o.y = packbf(v[2], v[3]);
            o.z = packbf(v[4], v[5]); o.w = packbf(v[6], v[7]);
            *(uint4*)((uint*)Pb + (size_t)gr * 256 + tx * 4) = o;
        }
    }
}

// ---------------------------------------------------------------------------
// K7: gate = sigmoid(G[v]·W_g2 + b_g2); out = gate*h_in_n + (1-gate)*h_out_n + x
// ---------------------------------------------------------------------------
__global__ __launch_bounds__(THREADS)
void finalize(const ushort* __restrict__ Pb,
              const float* __restrict__ W_g2, const float* __restrict__ b_g2,
              const float* __restrict__ x, float* __restrict__ out, int M)
{
    const int lane = threadIdx.x & 63;
    const int wid  = threadIdx.x >> 6;
    const int v    = blockIdx.x * 4 + wid;
    if (v >= M) return;

    const uint* row = (const uint*)Pb + (size_t)v * 256;

    const uint  gv = row[lane];                      // G elems 2*lane, 2*lane+1
    const float2 w2 = *(const float2*)(W_g2 + 2 * lane);
    float part = blo(gv) * w2.x + bhi(gv) * w2.y;
#pragma unroll
    for (int off = 32; off; off >>= 1) part += __shfl_xor(part, off);
    const float gate = 1.f / (1.f + expf(-(part + b_g2[0])));

    const uint hiv = row[128 + lane];                // h_in_norm
    const uint hov = row[192 + lane];                // h_out_norm
    const float2 xv = *(const float2*)(x + (size_t)v * 128 + 2 * lane);

    float2 o;
    o.x = gate * blo(hiv) + (1.f - gate) * blo(hov) + xv.x;
    o.y = gate * bhi(hiv) + (1.f - gate) * bhi(hov) + xv.y;
    *(float2*)(out + (size_t)v * 128 + 2 * lane) = o;
}

// ---------------------------------------------------------------------------
extern "C" void kernel_launch(void* const* d_in, const int* in_sizes, int n_in,
                              void* d_out, int out_size, void* d_ws, size_t ws_size,
                              hipStream_t stream)
{
    const float* x     = (const float*)d_in[0];
    const int*   src   = (const int*)  d_in[1];
    const int*   dst   = (const int*)  d_in[2];
    const float* cnts  = (const float*)d_in[3];
    const float* W_sd  = (const float*)d_in[4];
    const float* b_sd  = (const float*)d_in[5];
    const float* W_ds  = (const float*)d_in[6];
    const float* b_ds  = (const float*)d_in[7];
    const float* W_l1  = (const float*)d_in[8];
    const float* b_l1  = (const float*)d_in[9];
    const float* W_l2  = (const float*)d_in[10];
    const float* b_l2  = (const float*)d_in[11];
    const float* W_g1  = (const float*)d_in[12];
    const float* b_g1  = (const float*)d_in[13];
    const float* W_g2  = (const float*)d_in[14];
    const float* b_g2  = (const float*)d_in[15];

    const int M = in_sizes[0] / 128;
    const int E = in_sizes[1];

    // workspace:
    //   Pb      : M*512 bf16 (1 KB/row)
    //   cnt_in, cnt_out, cur_in, cur_out : int[M]   (zeroed)
    //   deg_in, deg_out                  : float[M] (zeroed)
    //   off_in, off_out                  : int[M]
    //   uw_in, uw_out                    : float2[E]
    ushort* Pb      = (ushort*)d_ws;
    int*    cnt_in  = (int*)(Pb + (size_t)M * 512);
    int*    cnt_out = cnt_in + M;
    int*    cur_in  = cnt_out + M;
    int*    cur_out = cur_in + M;
    float*  deg_in  = (float*)(cur_out + M);
    float*  deg_out = deg_in + M;
    int*    off_in  = (int*)(deg_out + M);
    int*    off_out = off_in + M;
    float2* uw_in   = (float2*)(off_out + M);
    float2* uw_out  = uw_in + E;

    // zero cnt_in..deg_out (6 contiguous M-arrays)
    hipMemsetAsync(cnt_in, 0, 6 * (size_t)M * sizeof(int), stream);

    dim3 g1((M + BM - 1) / BM, 4);
    gemm_node<<<g1, THREADS, 0, stream>>>(x, M, W_sd, b_sd, W_ds, b_ds, W_l1, b_l1, Pb);

    edge_count<<<(E + THREADS - 1) / THREADS, THREADS, 0, stream>>>(
        src, dst, cnts, cnt_in, cnt_out, deg_in, deg_out, E);

    scan2<<<2, 1024, 0, stream>>>(cnt_in, off_in, cnt_out, off_out, M);

    edge_lcs_fill<<<(E + 15) / 16, THREADS, 0, stream>>>(
        Pb, src, dst, cnts, W_l2, b_l2, off_in, off_out, cur_in, cur_out,
        uw_in, uw_out, E);

    node_agg<<<(2 * M + 3) / 4, THREADS, 0, stream>>>(
        Pb, uw_in, uw_out, off_in, cnt_in, off_out, cnt_out, deg_in, deg_out, M);

    gemm_gate<<<(M + BM - 1) / BM, THREADS, 0, stream>>>(Pb, M, W_g1, b_g1);

    finalize<<<(M + 3) / 4, THREADS, 0, stream>>>(Pb, W_g2, b_g2, x, (float*)d_out, M);
}

// Round 6
// 427.164 us; speedup vs baseline: 2.5683x; 1.0914x over previous
//
#include <hip/hip_runtime.h>
#include <math.h>

typedef unsigned int uint;
typedef unsigned long long ull;

#define THREADS 256
#define BM 64
#define BN 128
#define BK 32
#define APAD 36

// ---- bf16 helpers (storage-only; all math in fp32) ------------------------
__device__ __forceinline__ float blo(uint u) { return __uint_as_float(u << 16); }
__device__ __forceinline__ float bhi(uint u) { return __uint_as_float(u & 0xffff0000u); }
__device__ __forceinline__ uint  bf16r(float x) {           // RTNE
    uint u = __float_as_uint(x);
    return (u + 0x7fffu + ((u >> 16) & 1u)) >> 16;
}
__device__ __forceinline__ uint packbf(float lo, float hi) {
    return bf16r(lo) | (bf16r(hi) << 16);
}

// ---------------------------------------------------------------------------
// K1 (fused): blockIdx.y == 0  -> edge counting via packed 64-bit atomics
//             (cnt in hi32, integer-valued weighted degree in lo32);
//             blockIdx.y 1..4 -> GEMM group grp = y-1:
//             P[n, 0:512] (bf16) = x[n] @ [W_sd | W_ds | W_l1t | W_l1b] + bias
//             elems: p_sd 0..127 | p_ds 128..255 | a(+b_l1) 256..383 | bb 384..511
// Counting blocks are dispatched first (y=0, x-fastest) and are fabric-bound
// with an idle VALU; they overlap with the VALU-bound GEMM blocks.
// ---------------------------------------------------------------------------
__global__ __launch_bounds__(THREADS)
void gemm_node_count(const float* __restrict__ X, int M,
                     const float* __restrict__ W_sd, const float* __restrict__ b_sd,
                     const float* __restrict__ W_ds, const float* __restrict__ b_ds,
                     const float* __restrict__ W_l1, const float* __restrict__ b_l1,
                     ushort* __restrict__ Pb,
                     const int* __restrict__ src, const int* __restrict__ dst,
                     const float* __restrict__ counts,
                     ull* __restrict__ packed_in, ull* __restrict__ packed_out,
                     int E)
{
    __shared__ float As[BM][APAD];
    __shared__ float Bs[BK][BN];

    const int tid = threadIdx.x;

    if (blockIdx.y == 0) {
        // ---------------- edge counting path ----------------
        const int stride = gridDim.x * THREADS;
        for (int e = blockIdx.x * THREADS + tid; e < E; e += stride) {
            const int  s = src[e];
            const int  d = dst[e];
            const uint c = (uint)counts[e];          // counts are integer-valued
            const ull  pv = (1ULL << 32) | (ull)c;
            atomicAdd(packed_in + d, pv);
            atomicAdd(packed_out + s, pv);
        }
        return;
    }

    // ---------------- GEMM path ----------------
    const int m0  = blockIdx.x * BM;
    const int grp = blockIdx.y - 1;

    const float* B;
    const float* bias;
    if (grp == 0)      { B = W_sd;               bias = b_sd; }
    else if (grp == 1) { B = W_ds;               bias = b_ds; }
    else if (grp == 2) { B = W_l1;               bias = b_l1; }
    else               { B = W_l1 + 128 * 128;   bias = nullptr; }

    const int ty = tid >> 4;
    const int tx = tid & 15;

    float acc[4][8];
#pragma unroll
    for (int i = 0; i < 4; ++i)
#pragma unroll
        for (int j = 0; j < 8; ++j) acc[i][j] = 0.f;

    const int lrow = tid >> 3;
    const int lc4  = tid & 7;

    for (int k0 = 0; k0 < 128; k0 += BK) {
#pragma unroll
        for (int p = 0; p < 2; ++p) {
            int r  = lrow + p * 32;
            int gr = m0 + r; if (gr >= M) gr = M - 1;
            const float4 v = *(const float4*)(X + (size_t)gr * 128 + k0 + lc4 * 4);
            *(float4*)(&As[r][lc4 * 4]) = v;
        }
#pragma unroll
        for (int i = 0; i < 4; ++i) {
            int idx = tid + i * 256;
            int kr  = idx >> 5;
            int c4  = idx & 31;
            const float4 v = *(const float4*)(B + (size_t)(k0 + kr) * 128 + c4 * 4);
            *(float4*)(&Bs[kr][c4 * 4]) = v;
        }
        __syncthreads();

#pragma unroll
        for (int k = 0; k < BK; ++k) {
            float a[4];
#pragma unroll
            for (int i = 0; i < 4; ++i) a[i] = As[ty * 4 + i][k];
            const float4 b0 = *(const float4*)(&Bs[k][tx * 8]);
            const float4 b1 = *(const float4*)(&Bs[k][tx * 8 + 4]);
            const float bb[8] = {b0.x, b0.y, b0.z, b0.w, b1.x, b1.y, b1.z, b1.w};
#pragma unroll
            for (int i = 0; i < 4; ++i)
#pragma unroll
                for (int j = 0; j < 8; ++j)
                    acc[i][j] = fmaf(a[i], bb[j], acc[i][j]);
        }
        __syncthreads();
    }

#pragma unroll
    for (int i = 0; i < 4; ++i) {
        int gr = m0 + ty * 4 + i;
        if (gr < M) {
            float v[8];
#pragma unroll
            for (int j = 0; j < 8; ++j) {
                float bv = bias ? bias[tx * 8 + j] : 0.f;
                v[j] = acc[i][j] + bv;
            }
            uint4 o;
            o.x = packbf(v[0], v[1]); o.y = packbf(v[2], v[3]);
            o.z = packbf(v[4], v[5]); o.w = packbf(v[6], v[7]);
            *(uint4*)((uint*)Pb + (size_t)gr * 256 + grp * 64 + tx * 4) = o;
        }
    }
}

// ---------------------------------------------------------------------------
// K3: exclusive scan of hi32(packed) -> off (one block per direction)
// ---------------------------------------------------------------------------
__global__ __launch_bounds__(1024)
void scan2(const ull* __restrict__ packed_in, int* __restrict__ off_in,
           const ull* __restrict__ packed_out, int* __restrict__ off_out, int M)
{
    const ull* pk  = blockIdx.x ? packed_out : packed_in;
    int*       off = blockIdx.x ? off_out : off_in;

    __shared__ int sums[1024];
    const int t     = threadIdx.x;
    const int chunk = (M + 1023) >> 10;
    const int lo    = t * chunk;
    const int hi    = (lo + chunk < M) ? lo + chunk : M;

    int s = 0;
    for (int i = lo; i < hi; ++i) s += (int)(pk[i] >> 32);
    sums[t] = s;
    __syncthreads();

    for (int o = 1; o < 1024; o <<= 1) {
        int v = (t >= o) ? sums[t - o] : 0;
        __syncthreads();
        sums[t] += v;
        __syncthreads();
    }

    int run = (t > 0) ? sums[t - 1] : 0;
    for (int i = lo; i < hi; ++i) { off[i] = run; run += (int)(pk[i] >> 32); }
}

// ---------------------------------------------------------------------------
// K4: edge_lcs_fill — 4 edges/wave, 16 lanes/edge (uint4 = 8 bf16 per lane).
//     w = sigmoid(relu(a[s]+bb[d])·W_l2 + b_l2)*cnt; write (u,w) CSR slots.
// ---------------------------------------------------------------------------
__global__ __launch_bounds__(THREADS)
void edge_lcs_fill(const ushort* __restrict__ Pb,
                   const int* __restrict__ src, const int* __restrict__ dst,
                   const float* __restrict__ counts,
                   const float* __restrict__ W_l2, const float* __restrict__ b_l2,
                   const int* __restrict__ off_in, const int* __restrict__ off_out,
                   int* __restrict__ cur_in, int* __restrict__ cur_out,
                   float2* __restrict__ uw_in, float2* __restrict__ uw_out, int E)
{
    const int lane = threadIdx.x & 63;
    const int wid  = threadIdx.x >> 6;
    const int g    = lane >> 4;       // edge slot within wave (0..3)
    const int gl   = lane & 15;
    int e = (blockIdx.x * 4 + wid) * 4 + g;
    const bool valid = (e < E);
    if (!valid) e = E - 1;

    const int   s = src[e];
    const int   d = dst[e];
    const float c = counts[e];

    const uint* rs = (const uint*)Pb + (size_t)s * 256;
    const uint* rd = (const uint*)Pb + (size_t)d * 256;

    const uint4 av = ((const uint4*)(rs + 128))[gl];   // a  : elems 256..383
    const uint4 bv = ((const uint4*)(rd + 192))[gl];   // bb : elems 384..511

    const float4 wa = ((const float4*)W_l2)[gl * 2];
    const float4 wb = ((const float4*)W_l2)[gl * 2 + 1];

    float part =
        fmaxf(blo(av.x) + blo(bv.x), 0.f) * wa.x + fmaxf(bhi(av.x) + bhi(bv.x), 0.f) * wa.y +
        fmaxf(blo(av.y) + blo(bv.y), 0.f) * wa.z + fmaxf(bhi(av.y) + bhi(bv.y), 0.f) * wa.w +
        fmaxf(blo(av.z) + blo(bv.z), 0.f) * wb.x + fmaxf(bhi(av.z) + bhi(bv.z), 0.f) * wb.y +
        fmaxf(blo(av.w) + blo(bv.w), 0.f) * wb.z + fmaxf(bhi(av.w) + bhi(bv.w), 0.f) * wb.w;

    part += __shfl_xor(part, 1);
    part += __shfl_xor(part, 2);
    part += __shfl_xor(part, 4);
    part += __shfl_xor(part, 8);

    if (gl == 0 && valid) {
        const float lcs = 1.f / (1.f + expf(-(part + b_l2[0])));
        const float w   = lcs * c;
        const int r1 = atomicAdd(cur_in + d, 1);
        uw_in[off_in[d] + r1] = make_float2(__int_as_float(s), w);
        const int r2 = atomicAdd(cur_out + s, 1);
        uw_out[off_out[s] + r2] = make_float2(__int_as_float(d), w);
    }
}

// ---------------------------------------------------------------------------
// K5: node_agg — 1 wave per (node,dir), 4 edge-groups of 16 lanes (uint4 row
//     gather), uw[j+4] prefetched. Writes degree-normalized h_in -> elems
//     256..383, h_out -> 384..511 (bf16; a/bb dead). n/deg from packed.
// ---------------------------------------------------------------------------
__global__ __launch_bounds__(THREADS)
void node_agg(ushort* __restrict__ Pb,
              const float2* __restrict__ uw_in, const float2* __restrict__ uw_out,
              const int* __restrict__ off_in,  const int* __restrict__ off_out,
              const ull* __restrict__ packed_in, const ull* __restrict__ packed_out,
              int M)
{
    const int lane = threadIdx.x & 63;
    const int wid  = threadIdx.x >> 6;
    const int task = blockIdx.x * 4 + wid;
    if (task >= 2 * M) return;
    const int v   = task >> 1;
    const int dir = task & 1;    // 0: in (gather p_sd[src]), 1: out (gather p_ds[dst])

    const ull           pk   = dir ? packed_out[v] : packed_in[v];
    const int           n    = (int)(pk >> 32);
    const int           base = dir ? off_out[v] : off_in[v];
    const float2* __restrict__ uw = (dir ? uw_out : uw_in) + base;
    const int           uofs = dir ? 64 : 0;      // uint offset of p_ds / p_sd
    const int g  = lane >> 4;     // edge group 0..3
    const int gl = lane & 15;     // 8 elems per lane

    float a0 = 0.f, a1 = 0.f, a2 = 0.f, a3 = 0.f;
    float a4 = 0.f, a5 = 0.f, a6 = 0.f, a7 = 0.f;

    float2 p = (g < n) ? uw[g] : make_float2(0.f, 0.f);
    for (int j = g; j < n; j += 4) {
        const int jn = j + 4;
        const float2 pn = (jn < n) ? uw[jn] : make_float2(0.f, 0.f);  // prefetch
        const int    u = __float_as_int(p.x);
        const float  w = p.y;
        const uint4 pv = ((const uint4*)((const uint*)Pb + (size_t)u * 256 + uofs))[gl];
        a0 = fmaf(blo(pv.x), w, a0);
        a1 = fmaf(bhi(pv.x), w, a1);
        a2 = fmaf(blo(pv.y), w, a2);
        a3 = fmaf(bhi(pv.y), w, a3);
        a4 = fmaf(blo(pv.z), w, a4);
        a5 = fmaf(bhi(pv.z), w, a5);
        a6 = fmaf(blo(pv.w), w, a6);
        a7 = fmaf(bhi(pv.w), w, a7);
        p = pn;
    }
    // combine the 4 edge-groups (lanes gl, gl+16, gl+32, gl+48)
#define RED2(a) a += __shfl_xor(a, 16); a += __shfl_xor(a, 32);
    RED2(a0) RED2(a1) RED2(a2) RED2(a3) RED2(a4) RED2(a5) RED2(a6) RED2(a7)
#undef RED2

    if (g == 0) {
        const float dg = (float)(uint)(pk & 0xffffffffu);
        const float r  = 1.f / fmaxf(dg, 1.f);
        uint4 o;
        o.x = packbf(a0 * r, a1 * r);
        o.y = packbf(a2 * r, a3 * r);
        o.z = packbf(a4 * r, a5 * r);
        o.w = packbf(a6 * r, a7 * r);
        ((uint4*)((uint*)Pb + (size_t)v * 256 + (dir ? 192 : 128)))[gl] = o;
    }
}

// ---------------------------------------------------------------------------
// K6: G = relu([h_in_n | h_out_n] @ W_g1 + b_g1)  (A bf16 from P elems
//     256..511, K=256); G (bf16) -> P elems 0..127 (p_sd/p_ds dead)
// ---------------------------------------------------------------------------
__global__ __launch_bounds__(THREADS)
void gemm_gate(ushort* __restrict__ Pb, int M,
               const float* __restrict__ W_g1, const float* __restrict__ b_g1)
{
    __shared__ float As[BM][APAD];
    __shared__ float Bs[BK][BN];

    const int tid = threadIdx.x;
    const int m0  = blockIdx.x * BM;
    const int ty  = tid >> 4;
    const int tx  = tid & 15;

    float acc[4][8];
#pragma unroll
    for (int i = 0; i < 4; ++i)
#pragma unroll
        for (int j = 0; j < 8; ++j) acc[i][j] = 0.f;

    const int lrow = tid >> 3;
    const int lc4  = tid & 7;

    for (int k0 = 0; k0 < 256; k0 += BK) {
#pragma unroll
        for (int p = 0; p < 2; ++p) {
            int r  = lrow + p * 32;
            int gr = m0 + r; if (gr >= M) gr = M - 1;
            const uint2 raw = *(const uint2*)((const uint*)Pb + (size_t)gr * 256 + 128 + k0 / 2 + lc4 * 2);
            float4 v;
            v.x = blo(raw.x); v.y = bhi(raw.x); v.z = blo(raw.y); v.w = bhi(raw.y);
            *(float4*)(&As[r][lc4 * 4]) = v;
        }
#pragma unroll
        for (int i = 0; i < 4; ++i) {
            int idx = tid + i * 256;
            int kr  = idx >> 5;
            int c4  = idx & 31;
            const float4 v = *(const float4*)(W_g1 + (size_t)(k0 + kr) * 128 + c4 * 4);
            *(float4*)(&Bs[kr][c4 * 4]) = v;
        }
        __syncthreads();

#pragma unroll
        for (int k = 0; k < BK; ++k) {
            float a[4];
#pragma unroll
            for (int i = 0; i < 4; ++i) a[i] = As[ty * 4 + i][k];
            const float4 b0 = *(const float4*)(&Bs[k][tx * 8]);
            const float4 b1 = *(const float4*)(&Bs[k][tx * 8 + 4]);
            const float bb[8] = {b0.x, b0.y, b0.z, b0.w, b1.x, b1.y, b1.z, b1.w};
#pragma unroll
            for (int i = 0; i < 4; ++i)
#pragma unroll
                for (int j = 0; j < 8; ++j)
                    acc[i][j] = fmaf(a[i], bb[j], acc[i][j]);
        }
        __syncthreads();
    }

#pragma unroll
    for (int i = 0; i < 4; ++i) {
        int gr = m0 + ty * 4 + i;
        if (gr < M) {
            float v[8];
#pragma unroll
            for (int j = 0; j < 8; ++j)
                v[j] = fmaxf(acc[i][j] + b_g1[tx * 8 + j], 0.f);
            uint4 o;
            o.x = packbf(v[0], v[1]); o.y = packbf(v[2], v[3]);
            o.z = packbf(v[4], v[5]); o.w = packbf(v[6], v[7]);
            *(uint4*)((uint*)Pb + (size_t)gr * 256 + tx * 4) = o;
        }
    }
}

// ---------------------------------------------------------------------------
// K7: gate = sigmoid(G[v]·W_g2 + b_g2); out = gate*h_in_n + (1-gate)*h_out_n + x
// ---------------------------------------------------------------------------
__global__ __launch_bounds__(THREADS)
void finalize(const ushort* __restrict__ Pb,
              const float* __restrict__ W_g2, const float* __restrict__ b_g2,
              const float* __restrict__ x, float* __restrict__ out, int M)
{
    const int lane = threadIdx.x & 63;
    const int wid  = threadIdx.x >> 6;
    const int v    = blockIdx.x * 4 + wid;
    if (v >= M) return;

    const uint* row = (const uint*)Pb + (size_t)v * 256;

    const uint  gv = row[lane];                      // G elems 2*lane, 2*lane+1
    const float2 w2 = *(const float2*)(W_g2 + 2 * lane);
    float part = blo(gv) * w2.x + bhi(gv) * w2.y;
#pragma unroll
    for (int off = 32; off; off >>= 1) part += __shfl_xor(part, off);
    const float gate = 1.f / (1.f + expf(-(part + b_g2[0])));

    const uint hiv = row[128 + lane];                // h_in_norm
    const uint hov = row[192 + lane];                // h_out_norm
    const float2 xv = *(const float2*)(x + (size_t)v * 128 + 2 * lane);

    float2 o;
    o.x = gate * blo(hiv) + (1.f - gate) * blo(hov) + xv.x;
    o.y = gate * bhi(hiv) + (1.f - gate) * bhi(hov) + xv.y;
    *(float2*)(out + (size_t)v * 128 + 2 * lane) = o;
}

// ---------------------------------------------------------------------------
extern "C" void kernel_launch(void* const* d_in, const int* in_sizes, int n_in,
                              void* d_out, int out_size, void* d_ws, size_t ws_size,
                              hipStream_t stream)
{
    const float* x     = (const float*)d_in[0];
    const int*   src   = (const int*)  d_in[1];
    const int*   dst   = (const int*)  d_in[2];
    const float* cnts  = (const float*)d_in[3];
    const float* W_sd  = (const float*)d_in[4];
    const float* b_sd  = (const float*)d_in[5];
    const float* W_ds  = (const float*)d_in[6];
    const float* b_ds  = (const float*)d_in[7];
    const float* W_l1  = (const float*)d_in[8];
    const float* b_l1  = (const float*)d_in[9];
    const float* W_l2  = (const float*)d_in[10];
    const float* b_l2  = (const float*)d_in[11];
    const float* W_g1  = (const float*)d_in[12];
    const float* b_g1  = (const float*)d_in[13];
    const float* W_g2  = (const float*)d_in[14];
    const float* b_g2  = (const float*)d_in[15];

    const int M = in_sizes[0] / 128;
    const int E = in_sizes[1];

    // workspace:
    //   Pb         : M*512 bf16 (1 KB/row)
    //   packed_in  : ull[M]  (zeroed)  cnt<<32 | int(deg)
    //   packed_out : ull[M]  (zeroed)
    //   cur_in     : int[M]  (zeroed)
    //   cur_out    : int[M]  (zeroed)
    //   off_in, off_out : int[M]
    //   uw_in, uw_out   : float2[E]
    ushort* Pb         = (ushort*)d_ws;
    ull*    packed_in  = (ull*)(Pb + (size_t)M * 512);
    ull*    packed_out = packed_in + M;
    int*    cur_in     = (int*)(packed_out + M);
    int*    cur_out    = cur_in + M;
    int*    off_in     = cur_out + M;
    int*    off_out    = off_in + M;
    float2* uw_in      = (float2*)(off_out + M);
    float2* uw_out     = uw_in + E;

    // zero packed_in..cur_out (24*M bytes contiguous)
    hipMemsetAsync(packed_in, 0, 24 * (size_t)M, stream);

    const int gx = (M + BM - 1) / BM;       // 782
    dim3 g1(gx, 5);                         // y=0: counting, y=1..4: GEMM groups
    gemm_node_count<<<g1, THREADS, 0, stream>>>(
        x, M, W_sd, b_sd, W_ds, b_ds, W_l1, b_l1, Pb,
        src, dst, cnts, packed_in, packed_out, E);

    scan2<<<2, 1024, 0, stream>>>(packed_in, off_in, packed_out, off_out, M);

    edge_lcs_fill<<<(E + 15) / 16, THREADS, 0, stream>>>(
        Pb, src, dst, cnts, W_l2, b_l2, off_in, off_out, cur_in, cur_out,
        uw_in, uw_out, E);

    node_agg<<<(2 * M + 3) / 4, THREADS, 0, stream>>>(
        Pb, uw_in, uw_out, off_in, off_out, packed_in, packed_out, M);

    gemm_gate<<<(M + BM - 1) / BM, THREADS, 0, stream>>>(Pb, M, W_g1, b_g1);

    finalize<<<(M + 3) / 4, THREADS, 0, stream>>>(Pb, W_g2, b_g2, x, (float*)d_out, M);
}

// Round 7
// 305.625 us; speedup vs baseline: 3.5897x; 1.3977x over previous
//
#include <hip/hip_runtime.h>
#include <math.h>

typedef unsigned int uint;
typedef unsigned long long ull;

#define THREADS 256

typedef __attribute__((ext_vector_type(8))) short bf16x8;
typedef __attribute__((ext_vector_type(4))) float f32x4;

// ---- bf16 helpers (storage-only; math in fp32 / MFMA-fp32-accum) ----------
__device__ __forceinline__ float blo(uint u) { return __uint_as_float(u << 16); }
__device__ __forceinline__ float bhi(uint u) { return __uint_as_float(u & 0xffff0000u); }
__device__ __forceinline__ uint  bf16r(float x) {           // RTNE
    uint u = __float_as_uint(x);
    return (u + 0x7fffu + ((u >> 16) & 1u)) >> 16;
}
__device__ __forceinline__ uint packbf(float lo, float hi) {
    return bf16r(lo) | (bf16r(hi) << 16);
}

// ---------------------------------------------------------------------------
// K0: transpose weights to bf16 Wt[n][k] once.
//   y=0..3: {W_sd,W_ds,W_l1_top,W_l1_bot} -> Wt + y*16384   ([128n][128k])
//   y=4,5 : W_g1 k-halves -> Wtg1 [128n][256k], kofs=(y-4)*128
// ---------------------------------------------------------------------------
__global__ __launch_bounds__(THREADS)
void transpose_w(const float* __restrict__ W_sd, const float* __restrict__ W_ds,
                 const float* __restrict__ W_l1, const float* __restrict__ W_g1,
                 ushort* __restrict__ Wt, ushort* __restrict__ Wtg1)
{
    __shared__ float tile[32][33];
    const int y = blockIdx.y;
    const float* src;
    ushort* dst;
    int dstK, kofs;
    if (y < 4) {
        src = (y == 0) ? W_sd : (y == 1) ? W_ds : (y == 2) ? W_l1 : (W_l1 + 16384);
        dst = Wt + y * 16384; dstK = 128; kofs = 0;
    } else {
        src = W_g1 + (y - 4) * 16384;
        dst = Wtg1; dstK = 256; kofs = (y - 4) * 128;
    }
    const int tix = blockIdx.x;
    const int k0 = (tix & 3) * 32, n0 = (tix >> 2) * 32;
    const int t = threadIdx.x;

    {
        const int r = t >> 3, c8 = t & 7;
        const float4 f = *(const float4*)(src + (size_t)(k0 + r) * 128 + n0 + c8 * 4);
        tile[r][c8 * 4 + 0] = f.x; tile[r][c8 * 4 + 1] = f.y;
        tile[r][c8 * 4 + 2] = f.z; tile[r][c8 * 4 + 3] = f.w;
    }
    __syncthreads();
    {
        const int n = t >> 3, k8 = t & 7;
        const float v0 = tile[k8 * 4 + 0][n], v1 = tile[k8 * 4 + 1][n];
        const float v2 = tile[k8 * 4 + 2][n], v3 = tile[k8 * 4 + 3][n];
        uint2 o; o.x = packbf(v0, v1); o.y = packbf(v2, v3);
        *(uint2*)(dst + (size_t)(n0 + n) * dstK + kofs + k0 + k8 * 4) = o;
    }
}

// ---------------------------------------------------------------------------
// shared MFMA tile body: As 64x128 bf16 (16KB), Bt 128x128 bf16 (32KB),
// XOR-swizzle kbyte ^= (row&7)<<4 on both; 4 waves x 16 rows x 128 cols.
// ---------------------------------------------------------------------------
__device__ __forceinline__ void mfma_tile_compute(const char* AsB, const char* BtB,
                                                  int wv, int ln, f32x4 acc[8])
{
    const int mrow = wv * 16 + (ln & 15);
    const int kgb  = (ln >> 4) * 16;                 // k-group byte offset
#pragma unroll
    for (int kk = 0; kk < 4; ++kk) {
        const int kbyte = kk * 64 + kgb;
        const bf16x8 a = *(const bf16x8*)(AsB + mrow * 256 + (kbyte ^ ((mrow & 7) << 4)));
#pragma unroll
        for (int tt = 0; tt < 8; ++tt) {
            const int nrow = tt * 16 + (ln & 15);
            const bf16x8 b = *(const bf16x8*)(BtB + nrow * 256 + (kbyte ^ ((nrow & 7) << 4)));
            acc[tt] = __builtin_amdgcn_mfma_f32_16x16x32_bf16(a, b, acc[tt], 0, 0, 0);
        }
    }
}

// ---------------------------------------------------------------------------
// K1 (fused): y==0 -> (a) edge counting: 1 packed 64-bit atomic per edge
//                     (cnt<<32 | int deg) on dst only; (b) off_out boundary
//                     fill exploiting SORTED src (np.unique lex order).
//             y=1..4 -> MFMA GEMM group grp=y-1:
//             P[n, 0:512] (bf16) = x @ [W_sd|W_ds|W_l1t|W_l1b] + bias
// ---------------------------------------------------------------------------
__global__ __launch_bounds__(THREADS)
void gemm_node_count(const float* __restrict__ X, int M,
                     const ushort* __restrict__ Wt,
                     const float* __restrict__ b_sd, const float* __restrict__ b_ds,
                     const float* __restrict__ b_l1,
                     ushort* __restrict__ Pb,
                     const int* __restrict__ src, const int* __restrict__ dst,
                     const float* __restrict__ counts,
                     ull* __restrict__ packed_in, int* __restrict__ off_out,
                     int E)
{
    __shared__ __align__(16) char AsB[16384];
    __shared__ __align__(16) char BtB[32768];

    const int tid = threadIdx.x;

    if (blockIdx.y == 0) {
        const int stride = gridDim.x * THREADS;
        for (int e = blockIdx.x * THREADS + tid; e < E; e += stride) {
            const int  d = dst[e];
            const uint c = (uint)counts[e];
            atomicAdd(packed_in + d, (1ULL << 32) | (ull)c);
        }
        // off_out: first edge index with src >= v (src sorted non-decreasing)
        for (int e = blockIdx.x * THREADS + tid; e < E; e += stride) {
            const int cur  = src[e];
            const int prev = (e == 0) ? -1 : src[e - 1];
            for (int v = prev + 1; v <= cur; ++v) off_out[v] = e;
            if (e == E - 1)
                for (int v = cur + 1; v <= M; ++v) off_out[v] = E;
        }
        return;
    }

    const int m0  = blockIdx.x * 64;
    const int grp = blockIdx.y - 1;
    const float* bias = (grp == 0) ? b_sd : (grp == 1) ? b_ds : (grp == 2) ? b_l1 : nullptr;
    const ushort* Wsrc = Wt + grp * 16384;

    // ---- stage A (64 rows x 128 k, fp32 -> bf16, swizzled) ----
    {
        const int r = tid >> 2, seg = tid & 3;
        int gr = m0 + r; if (gr >= M) gr = M - 1;
        const float4* xs = (const float4*)(X + (size_t)gr * 128 + seg * 32);
#pragma unroll
        for (int i = 0; i < 4; ++i) {
            const float4 f0 = xs[i * 2], f1 = xs[i * 2 + 1];
            uint4 u;
            u.x = packbf(f0.x, f0.y); u.y = packbf(f0.z, f0.w);
            u.z = packbf(f1.x, f1.y); u.w = packbf(f1.z, f1.w);
            const int kbyte = seg * 64 + i * 16;
            *(uint4*)(AsB + r * 256 + (kbyte ^ ((r & 7) << 4))) = u;
        }
    }
    // ---- stage Bt (128 n-rows x 128 k, already bf16, swizzled) ----
    {
        const int rn = tid >> 1, sg = tid & 1;
        const uint4* ws = (const uint4*)(Wsrc + (size_t)rn * 128 + sg * 64);
#pragma unroll
        for (int i = 0; i < 8; ++i) {
            const uint4 u = ws[i];
            const int kbyte = sg * 128 + i * 16;
            *(uint4*)(BtB + rn * 256 + (kbyte ^ ((rn & 7) << 4))) = u;
        }
    }
    __syncthreads();

    const int wv = tid >> 6, ln = tid & 63;
    f32x4 acc[8];
#pragma unroll
    for (int tt = 0; tt < 8; ++tt) acc[tt] = (f32x4){0.f, 0.f, 0.f, 0.f};

    mfma_tile_compute(AsB, BtB, wv, ln, acc);

    // ---- epilogue: bias, bf16, bounce through AsB, coalesced store ----
    __syncthreads();
#pragma unroll
    for (int tt = 0; tt < 8; ++tt) {
        const int n  = tt * 16 + (ln & 15);
        const float bv = bias ? bias[n] : 0.f;
#pragma unroll
        for (int r = 0; r < 4; ++r) {
            const int m = wv * 16 + ((ln >> 4) << 2) + r;
            ((ushort*)AsB)[m * 128 + n] = (ushort)bf16r(acc[tt][r] + bv);
        }
    }
    __syncthreads();
    {
        const int rr = tid >> 2, sg2 = tid & 3;
        const int gr = m0 + rr;
        if (gr < M) {
            uint4* dstp = (uint4*)Pb + (size_t)gr * 64 + grp * 16 + sg2 * 4;
#pragma unroll
            for (int i = 0; i < 4; ++i)
                dstp[i] = *(const uint4*)(AsB + rr * 256 + (sg2 * 4 + i) * 16);
        }
    }
}

// ---------------------------------------------------------------------------
// K2: exclusive scan of hi32(packed_in) -> off_in (single block)
// ---------------------------------------------------------------------------
__global__ __launch_bounds__(1024)
void scan_in(const ull* __restrict__ packed_in, int* __restrict__ off_in, int M)
{
    __shared__ int sums[1024];
    const int t     = threadIdx.x;
    const int chunk = (M + 1023) >> 10;
    const int lo    = t * chunk;
    const int hi    = (lo + chunk < M) ? lo + chunk : M;

    int s = 0;
    for (int i = lo; i < hi; ++i) s += (int)(packed_in[i] >> 32);
    sums[t] = s;
    __syncthreads();

    for (int o = 1; o < 1024; o <<= 1) {
        int v = (t >= o) ? sums[t - o] : 0;
        __syncthreads();
        sums[t] += v;
        __syncthreads();
    }

    int run = (t > 0) ? sums[t - 1] : 0;
    for (int i = lo; i < hi; ++i) { off_in[i] = run; run += (int)(packed_in[i] >> 32); }
}

// ---------------------------------------------------------------------------
// K3: edge_lcs_fill — 4 edges/wave, 16 lanes/edge.
//     w = sigmoid(relu(a[s]+bb[d])·W_l2 + b_l2)*cnt;
//     write w_e[e] (coalesced) + in-CSR slot (u,w) via cur_in atomic.
// ---------------------------------------------------------------------------
__global__ __launch_bounds__(THREADS)
void edge_lcs_fill(const ushort* __restrict__ Pb,
                   const int* __restrict__ src, const int* __restrict__ dst,
                   const float* __restrict__ counts,
                   const float* __restrict__ W_l2, const float* __restrict__ b_l2,
                   const int* __restrict__ off_in, int* __restrict__ cur_in,
                   float* __restrict__ w_e, float2* __restrict__ uw_in, int E)
{
    const int lane = threadIdx.x & 63;
    const int wid  = threadIdx.x >> 6;
    const int g    = lane >> 4;
    const int gl   = lane & 15;
    int e = (blockIdx.x * 4 + wid) * 4 + g;
    const bool valid = (e < E);
    if (!valid) e = E - 1;

    const int   s = src[e];
    const int   d = dst[e];
    const float c = counts[e];

    const uint* rs = (const uint*)Pb + (size_t)s * 256;
    const uint* rd = (const uint*)Pb + (size_t)d * 256;

    const uint4 av = ((const uint4*)(rs + 128))[gl];   // a  : elems 256..383
    const uint4 bv = ((const uint4*)(rd + 192))[gl];   // bb : elems 384..511

    const float4 wa = ((const float4*)W_l2)[gl * 2];
    const float4 wb = ((const float4*)W_l2)[gl * 2 + 1];

    float part =
        fmaxf(blo(av.x) + blo(bv.x), 0.f) * wa.x + fmaxf(bhi(av.x) + bhi(bv.x), 0.f) * wa.y +
        fmaxf(blo(av.y) + blo(bv.y), 0.f) * wa.z + fmaxf(bhi(av.y) + bhi(bv.y), 0.f) * wa.w +
        fmaxf(blo(av.z) + blo(bv.z), 0.f) * wb.x + fmaxf(bhi(av.z) + bhi(bv.z), 0.f) * wb.y +
        fmaxf(blo(av.w) + blo(bv.w), 0.f) * wb.z + fmaxf(bhi(av.w) + bhi(bv.w), 0.f) * wb.w;

    part += __shfl_xor(part, 1);
    part += __shfl_xor(part, 2);
    part += __shfl_xor(part, 4);
    part += __shfl_xor(part, 8);

    if (gl == 0 && valid) {
        const float lcs = 1.f / (1.f + expf(-(part + b_l2[0])));
        const float w   = lcs * c;
        w_e[e] = w;
        const int r1 = atomicAdd(cur_in + d, 1);
        uw_in[off_in[d] + r1] = make_float2(__int_as_float(s), w);
    }
}

// ---------------------------------------------------------------------------
// K4: node_agg — 1 wave per (node,dir), 4 edge-groups of 16 lanes (uint4 row
//     gather). dir=0 (in): walk uw_in CSR; dir=1 (out): walk sorted-src run
//     [off_out[v], off_out[v+1]) directly over dst/w_e/counts. Writes
//     degree-normalized h_in -> elems 256..383, h_out -> 384..511.
// ---------------------------------------------------------------------------
__global__ __launch_bounds__(THREADS)
void node_agg(ushort* __restrict__ Pb,
              const float2* __restrict__ uw_in,
              const int* __restrict__ off_in, const ull* __restrict__ packed_in,
              const int* __restrict__ off_out,
              const int* __restrict__ dst, const float* __restrict__ w_e,
              const float* __restrict__ counts, int M)
{
    const int lane = threadIdx.x & 63;
    const int wid  = threadIdx.x >> 6;
    const int task = blockIdx.x * 4 + wid;
    if (task >= 2 * M) return;
    const int v   = task >> 1;
    const int dir = task & 1;

    const int g  = lane >> 4;
    const int gl = lane & 15;

    float a0 = 0.f, a1 = 0.f, a2 = 0.f, a3 = 0.f;
    float a4 = 0.f, a5 = 0.f, a6 = 0.f, a7 = 0.f;
    float dg = 0.f;

    if (dir == 0) {
        const ull pk = packed_in[v];
        const int n  = (int)(pk >> 32);
        dg = (g == 0) ? (float)(uint)(pk & 0xffffffffu) : 0.f;
        const float2* __restrict__ uw = uw_in + off_in[v];
        for (int j = g; j < n; j += 4) {
            const float2 p = uw[j];
            const int    u = __float_as_int(p.x);
            const float  w = p.y;
            const uint4 pv = ((const uint4*)((const uint*)Pb + (size_t)u * 256))[gl];
            a0 = fmaf(blo(pv.x), w, a0); a1 = fmaf(bhi(pv.x), w, a1);
            a2 = fmaf(blo(pv.y), w, a2); a3 = fmaf(bhi(pv.y), w, a3);
            a4 = fmaf(blo(pv.z), w, a4); a5 = fmaf(bhi(pv.z), w, a5);
            a6 = fmaf(blo(pv.w), w, a6); a7 = fmaf(bhi(pv.w), w, a7);
        }
    } else {
        const int base = off_out[v];
        const int end  = off_out[v + 1];
        for (int j = base + g; j < end; j += 4) {
            const int    u = dst[j];
            const float  w = w_e[j];
            dg += counts[j];
            const uint4 pv = ((const uint4*)((const uint*)Pb + (size_t)u * 256 + 64))[gl];
            a0 = fmaf(blo(pv.x), w, a0); a1 = fmaf(bhi(pv.x), w, a1);
            a2 = fmaf(blo(pv.y), w, a2); a3 = fmaf(bhi(pv.y), w, a3);
            a4 = fmaf(blo(pv.z), w, a4); a5 = fmaf(bhi(pv.z), w, a5);
            a6 = fmaf(blo(pv.w), w, a6); a7 = fmaf(bhi(pv.w), w, a7);
        }
    }

#define RED2(a) a += __shfl_xor(a, 16); a += __shfl_xor(a, 32);
    RED2(a0) RED2(a1) RED2(a2) RED2(a3) RED2(a4) RED2(a5) RED2(a6) RED2(a7) RED2(dg)
#undef RED2

    if (g == 0) {
        const float r = 1.f / fmaxf(dg, 1.f);
        uint4 o;
        o.x = packbf(a0 * r, a1 * r);
        o.y = packbf(a2 * r, a3 * r);
        o.z = packbf(a4 * r, a5 * r);
        o.w = packbf(a6 * r, a7 * r);
        ((uint4*)((uint*)Pb + (size_t)v * 256 + (dir ? 192 : 128)))[gl] = o;
    }
}

// ---------------------------------------------------------------------------
// K5: gemm_gate (MFMA) — G = relu([h_in_n|h_out_n](bf16, P elems 256..511)
//     @ W_g1 + b_g1), K=256 in two staged halves; G(bf16) -> P elems 0..127.
// ---------------------------------------------------------------------------
__global__ __launch_bounds__(THREADS)
void gemm_gate(ushort* __restrict__ Pb, int M,
               const ushort* __restrict__ Wtg1, const float* __restrict__ b_g1)
{
    __shared__ __align__(16) char AsB[16384];
    __shared__ __align__(16) char BtB[32768];

    const int tid = threadIdx.x;
    const int m0  = blockIdx.x * 64;
    const int wv = tid >> 6, ln = tid & 63;

    f32x4 acc[8];
#pragma unroll
    for (int tt = 0; tt < 8; ++tt) acc[tt] = (f32x4){0.f, 0.f, 0.f, 0.f};

    for (int h = 0; h < 2; ++h) {
        if (h) __syncthreads();
        // stage A half: P uint4 [32 + h*16 + 0..15] per row
        {
            const int r = tid >> 2, seg = tid & 3;
            int gr = m0 + r; if (gr >= M) gr = M - 1;
            const uint4* ps = (const uint4*)Pb + (size_t)gr * 64 + 32 + h * 16 + seg * 4;
#pragma unroll
            for (int i = 0; i < 4; ++i) {
                const uint4 u = ps[i];
                const int kbyte = seg * 64 + i * 16;
                *(uint4*)(AsB + r * 256 + (kbyte ^ ((r & 7) << 4))) = u;
            }
        }
        // stage Bt half from Wtg1 [128n][256k]
        {
            const int rn = tid >> 1, sg = tid & 1;
            const uint4* ws = (const uint4*)Wtg1 + (size_t)rn * 32 + h * 16 + sg * 8;
#pragma unroll
            for (int i = 0; i < 8; ++i) {
                const uint4 u = ws[i];
                const int kbyte = sg * 128 + i * 16;
                *(uint4*)(BtB + rn * 256 + (kbyte ^ ((rn & 7) << 4))) = u;
            }
        }
        __syncthreads();
        mfma_tile_compute(AsB, BtB, wv, ln, acc);
    }

    __syncthreads();
#pragma unroll
    for (int tt = 0; tt < 8; ++tt) {
        const int n = tt * 16 + (ln & 15);
        const float bv = b_g1[n];
#pragma unroll
        for (int r = 0; r < 4; ++r) {
            const int m = wv * 16 + ((ln >> 4) << 2) + r;
            ((ushort*)AsB)[m * 128 + n] = (ushort)bf16r(fmaxf(acc[tt][r] + bv, 0.f));
        }
    }
    __syncthreads();
    {
        const int rr = tid >> 2, sg2 = tid & 3;
        const int gr = m0 + rr;
        if (gr < M) {
            uint4* dstp = (uint4*)Pb + (size_t)gr * 64 + sg2 * 4;
#pragma unroll
            for (int i = 0; i < 4; ++i)
                dstp[i] = *(const uint4*)(AsB + rr * 256 + (sg2 * 4 + i) * 16);
        }
    }
}

// ---------------------------------------------------------------------------
// K6: gate = sigmoid(G[v]·W_g2 + b_g2); out = gate*h_in_n + (1-gate)*h_out_n + x
// ---------------------------------------------------------------------------
__global__ __launch_bounds__(THREADS)
void finalize(const ushort* __restrict__ Pb,
              const float* __restrict__ W_g2, const float* __restrict__ b_g2,
              const float* __restrict__ x, float* __restrict__ out, int M)
{
    const int lane = threadIdx.x & 63;
    const int wid  = threadIdx.x >> 6;
    const int v    = blockIdx.x * 4 + wid;
    if (v >= M) return;

    const uint* row = (const uint*)Pb + (size_t)v * 256;

    const uint  gv = row[lane];
    const float2 w2 = *(const float2*)(W_g2 + 2 * lane);
    float part = blo(gv) * w2.x + bhi(gv) * w2.y;
#pragma unroll
    for (int off = 32; off; off >>= 1) part += __shfl_xor(part, off);
    const float gate = 1.f / (1.f + expf(-(part + b_g2[0])));

    const uint hiv = row[128 + lane];
    const uint hov = row[192 + lane];
    const float2 xv = *(const float2*)(x + (size_t)v * 128 + 2 * lane);

    float2 o;
    o.x = gate * blo(hiv) + (1.f - gate) * blo(hov) + xv.x;
    o.y = gate * bhi(hiv) + (1.f - gate) * bhi(hov) + xv.y;
    *(float2*)(out + (size_t)v * 128 + 2 * lane) = o;
}

// ---------------------------------------------------------------------------
extern "C" void kernel_launch(void* const* d_in, const int* in_sizes, int n_in,
                              void* d_out, int out_size, void* d_ws, size_t ws_size,
                              hipStream_t stream)
{
    const float* x     = (const float*)d_in[0];
    const int*   src   = (const int*)  d_in[1];
    const int*   dst   = (const int*)  d_in[2];
    const float* cnts  = (const float*)d_in[3];
    const float* W_sd  = (const float*)d_in[4];
    const float* b_sd  = (const float*)d_in[5];
    const float* W_ds  = (const float*)d_in[6];
    const float* b_ds  = (const float*)d_in[7];
    const float* W_l1  = (const float*)d_in[8];
    const float* b_l1  = (const float*)d_in[9];
    const float* W_l2  = (const float*)d_in[10];
    const float* b_l2  = (const float*)d_in[11];
    const float* W_g1  = (const float*)d_in[12];
    const float* b_g1  = (const float*)d_in[13];
    const float* W_g2  = (const float*)d_in[14];
    const float* b_g2  = (const float*)d_in[15];

    const int M = in_sizes[0] / 128;
    const int E = in_sizes[1];

    // workspace:
    //   Pb        : M*512 bf16
    //   Wt        : 4*128*128 bf16 (transposed node weights)
    //   Wtg1      : 128*256 bf16   (transposed gate weight)
    //   packed_in : ull[M] (zeroed)   cnt<<32 | int(deg)
    //   cur_in    : int[M] (zeroed)
    //   uw_in     : float2[E]
    //   off_in    : int[M]
    //   off_out   : int[M+1]
    //   w_e       : float[E]
    ushort* Pb        = (ushort*)d_ws;
    ushort* Wt        = Pb + (size_t)M * 512;
    ushort* Wtg1      = Wt + 4 * 16384;
    ull*    packed_in = (ull*)(Wtg1 + 32768);
    int*    cur_in    = (int*)(packed_in + M);
    float2* uw_in     = (float2*)(cur_in + M);   // 12M bytes after packed_in ok (8B aligned)
    int*    off_in    = (int*)(uw_in + E);
    int*    off_out   = off_in + M;
    float*  w_e       = (float*)(off_out + M + 1);

    // zero packed_in + cur_in (contiguous 12*M bytes)
    hipMemsetAsync(packed_in, 0, 12 * (size_t)M, stream);

    transpose_w<<<dim3(16, 6), THREADS, 0, stream>>>(W_sd, W_ds, W_l1, W_g1, Wt, Wtg1);

    const int gx = (M + 63) / 64;
    gemm_node_count<<<dim3(gx, 5), THREADS, 0, stream>>>(
        x, M, Wt, b_sd, b_ds, b_l1, Pb, src, dst, cnts, packed_in, off_out, E);

    scan_in<<<1, 1024, 0, stream>>>(packed_in, off_in, M);

    edge_lcs_fill<<<(E + 15) / 16, THREADS, 0, stream>>>(
        Pb, src, dst, cnts, W_l2, b_l2, off_in, cur_in, w_e, uw_in, E);

    node_agg<<<(2 * M + 3) / 4, THREADS, 0, stream>>>(
        Pb, uw_in, off_in, packed_in, off_out, dst, w_e, cnts, M);

    gemm_gate<<<gx, THREADS, 0, stream>>>(Pb, M, Wtg1, b_g1);

    finalize<<<(M + 3) / 4, THREADS, 0, stream>>>(Pb, W_g2, b_g2, x, (float*)d_out, M);
}

// Round 8
// 211.456 us; speedup vs baseline: 5.1883x; 1.4453x over previous
//
#include <hip/hip_runtime.h>
#include <math.h>

typedef unsigned int uint;
typedef unsigned long long ull;

#define THREADS 256

typedef __attribute__((ext_vector_type(8))) short bf16x8;
typedef __attribute__((ext_vector_type(4))) float f32x4;

// ---- bf16 helpers (storage-only; math in fp32 / MFMA-fp32-accum) ----------
__device__ __forceinline__ float blo(uint u) { return __uint_as_float(u << 16); }
__device__ __forceinline__ float bhi(uint u) { return __uint_as_float(u & 0xffff0000u); }
__device__ __forceinline__ uint  bf16r(float x) {           // RTNE
    uint u = __float_as_uint(x);
    return (u + 0x7fffu + ((u >> 16) & 1u)) >> 16;
}
__device__ __forceinline__ uint packbf(float lo, float hi) {
    return bf16r(lo) | (bf16r(hi) << 16);
}

// ---------------------------------------------------------------------------
// K0: transpose weights to bf16 Wt[n][k] once.
// ---------------------------------------------------------------------------
__global__ __launch_bounds__(THREADS)
void transpose_w(const float* __restrict__ W_sd, const float* __restrict__ W_ds,
                 const float* __restrict__ W_l1, const float* __restrict__ W_g1,
                 ushort* __restrict__ Wt, ushort* __restrict__ Wtg1)
{
    __shared__ float tile[32][33];
    const int y = blockIdx.y;
    const float* src;
    ushort* dst;
    int dstK, kofs;
    if (y < 4) {
        src = (y == 0) ? W_sd : (y == 1) ? W_ds : (y == 2) ? W_l1 : (W_l1 + 16384);
        dst = Wt + y * 16384; dstK = 128; kofs = 0;
    } else {
        src = W_g1 + (y - 4) * 16384;
        dst = Wtg1; dstK = 256; kofs = (y - 4) * 128;
    }
    const int tix = blockIdx.x;
    const int k0 = (tix & 3) * 32, n0 = (tix >> 2) * 32;
    const int t = threadIdx.x;

    {
        const int r = t >> 3, c8 = t & 7;
        const float4 f = *(const float4*)(src + (size_t)(k0 + r) * 128 + n0 + c8 * 4);
        tile[r][c8 * 4 + 0] = f.x; tile[r][c8 * 4 + 1] = f.y;
        tile[r][c8 * 4 + 2] = f.z; tile[r][c8 * 4 + 3] = f.w;
    }
    __syncthreads();
    {
        const int n = t >> 3, k8 = t & 7;
        const float v0 = tile[k8 * 4 + 0][n], v1 = tile[k8 * 4 + 1][n];
        const float v2 = tile[k8 * 4 + 2][n], v3 = tile[k8 * 4 + 3][n];
        uint2 o; o.x = packbf(v0, v1); o.y = packbf(v2, v3);
        *(uint2*)(dst + (size_t)(n0 + n) * dstK + kofs + k0 + k8 * 4) = o;
    }
}

// ---------------------------------------------------------------------------
// shared MFMA tile body: As 64x128 bf16 (16KB), Bt 128x128 bf16 (32KB),
// XOR-swizzle kbyte ^= (row&7)<<4 on both; 4 waves x 16 rows x 128 cols.
// ---------------------------------------------------------------------------
__device__ __forceinline__ void mfma_tile_compute(const char* AsB, const char* BtB,
                                                  int wv, int ln, f32x4 acc[8])
{
    const int mrow = wv * 16 + (ln & 15);
    const int kgb  = (ln >> 4) * 16;                 // k-group byte offset
#pragma unroll
    for (int kk = 0; kk < 4; ++kk) {
        const int kbyte = kk * 64 + kgb;
        const bf16x8 a = *(const bf16x8*)(AsB + mrow * 256 + (kbyte ^ ((mrow & 7) << 4)));
#pragma unroll
        for (int tt = 0; tt < 8; ++tt) {
            const int nrow = tt * 16 + (ln & 15);
            const bf16x8 b = *(const bf16x8*)(BtB + nrow * 256 + (kbyte ^ ((nrow & 7) << 4)));
            acc[tt] = __builtin_amdgcn_mfma_f32_16x16x32_bf16(a, b, acc[tt], 0, 0, 0);
        }
    }
}

// ---------------------------------------------------------------------------
// K1 (fused): y==0 -> edge counting (1 packed atomic/edge on dst) + off_out
//             boundary fill from SORTED src; y=1..4 -> MFMA GEMM groups.
// ---------------------------------------------------------------------------
__global__ __launch_bounds__(THREADS)
void gemm_node_count(const float* __restrict__ X, int M,
                     const ushort* __restrict__ Wt,
                     const float* __restrict__ b_sd, const float* __restrict__ b_ds,
                     const float* __restrict__ b_l1,
                     ushort* __restrict__ Pb,
                     const int* __restrict__ src, const int* __restrict__ dst,
                     const float* __restrict__ counts,
                     ull* __restrict__ packed_in, int* __restrict__ off_out,
                     int E)
{
    __shared__ __align__(16) char AsB[16384];
    __shared__ __align__(16) char BtB[32768];

    const int tid = threadIdx.x;

    if (blockIdx.y == 0) {
        const int stride = gridDim.x * THREADS;
        for (int e = blockIdx.x * THREADS + tid; e < E; e += stride) {
            const int  d = dst[e];
            const uint c = (uint)counts[e];
            atomicAdd(packed_in + d, (1ULL << 32) | (ull)c);
        }
        // off_out: first edge index with src >= v (src sorted non-decreasing)
        for (int e = blockIdx.x * THREADS + tid; e < E; e += stride) {
            const int cur  = src[e];
            const int prev = (e == 0) ? -1 : src[e - 1];
            for (int v = prev + 1; v <= cur; ++v) off_out[v] = e;
            if (e == E - 1)
                for (int v = cur + 1; v <= M; ++v) off_out[v] = E;
        }
        return;
    }

    const int m0  = blockIdx.x * 64;
    const int grp = blockIdx.y - 1;
    const float* bias = (grp == 0) ? b_sd : (grp == 1) ? b_ds : (grp == 2) ? b_l1 : nullptr;
    const ushort* Wsrc = Wt + grp * 16384;

    // ---- stage A (64 rows x 128 k, fp32 -> bf16, swizzled) ----
    {
        const int r = tid >> 2, seg = tid & 3;
        int gr = m0 + r; if (gr >= M) gr = M - 1;
        const float4* xs = (const float4*)(X + (size_t)gr * 128 + seg * 32);
#pragma unroll
        for (int i = 0; i < 4; ++i) {
            const float4 f0 = xs[i * 2], f1 = xs[i * 2 + 1];
            uint4 u;
            u.x = packbf(f0.x, f0.y); u.y = packbf(f0.z, f0.w);
            u.z = packbf(f1.x, f1.y); u.w = packbf(f1.z, f1.w);
            const int kbyte = seg * 64 + i * 16;
            *(uint4*)(AsB + r * 256 + (kbyte ^ ((r & 7) << 4))) = u;
        }
    }
    // ---- stage Bt (128 n-rows x 128 k, already bf16, swizzled) ----
    {
        const int rn = tid >> 1, sg = tid & 1;
        const uint4* ws = (const uint4*)(Wsrc + (size_t)rn * 128 + sg * 64);
#pragma unroll
        for (int i = 0; i < 8; ++i) {
            const uint4 u = ws[i];
            const int kbyte = sg * 128 + i * 16;
            *(uint4*)(BtB + rn * 256 + (kbyte ^ ((rn & 7) << 4))) = u;
        }
    }
    __syncthreads();

    const int wv = tid >> 6, ln = tid & 63;
    f32x4 acc[8];
#pragma unroll
    for (int tt = 0; tt < 8; ++tt) acc[tt] = (f32x4){0.f, 0.f, 0.f, 0.f};

    mfma_tile_compute(AsB, BtB, wv, ln, acc);

    // ---- epilogue: bias, bf16, bounce through AsB, coalesced store ----
    __syncthreads();
#pragma unroll
    for (int tt = 0; tt < 8; ++tt) {
        const int n  = tt * 16 + (ln & 15);
        const float bv = bias ? bias[n] : 0.f;
#pragma unroll
        for (int r = 0; r < 4; ++r) {
            const int m = wv * 16 + ((ln >> 4) << 2) + r;
            ((ushort*)AsB)[m * 128 + n] = (ushort)bf16r(acc[tt][r] + bv);
        }
    }
    __syncthreads();
    {
        const int rr = tid >> 2, sg2 = tid & 3;
        const int gr = m0 + rr;
        if (gr < M) {
            uint4* dstp = (uint4*)Pb + (size_t)gr * 64 + grp * 16 + sg2 * 4;
#pragma unroll
            for (int i = 0; i < 4; ++i)
                dstp[i] = *(const uint4*)(AsB + rr * 256 + (sg2 * 4 + i) * 16);
        }
    }
}

// ---------------------------------------------------------------------------
// K2a/b/c: hierarchical exclusive scan of hi32(packed_in) -> off_in.
//   p1: 256-elem block reduce -> bsum[b]
//   p2: single block (1024 thr) exclusive-scans bsum (NB <= 1024)
//   p3: per-block 256-wide scan + bsum[b] offset -> off_in
// ---------------------------------------------------------------------------
__global__ __launch_bounds__(256)
void scan_p1(const ull* __restrict__ packed_in, int* __restrict__ bsum, int M)
{
    __shared__ int s[256];
    const int t = threadIdx.x;
    const int i = blockIdx.x * 256 + t;
    s[t] = (i < M) ? (int)(packed_in[i] >> 32) : 0;
    __syncthreads();
#pragma unroll
    for (int o = 128; o; o >>= 1) {
        if (t < o) s[t] += s[t + o];
        __syncthreads();
    }
    if (t == 0) bsum[blockIdx.x] = s[0];
}

__global__ __launch_bounds__(1024)
void scan_p2(int* __restrict__ bsum, int NB)
{
    __shared__ int s[1024];
    const int t = threadIdx.x;
    const int v = (t < NB) ? bsum[t] : 0;
    s[t] = v;
    __syncthreads();
    for (int o = 1; o < 1024; o <<= 1) {
        const int u = (t >= o) ? s[t - o] : 0;
        __syncthreads();
        s[t] += u;
        __syncthreads();
    }
    if (t < NB) bsum[t] = s[t] - v;   // exclusive
}

__global__ __launch_bounds__(256)
void scan_p3(const ull* __restrict__ packed_in, const int* __restrict__ bsum,
             int* __restrict__ off_in, int M)
{
    __shared__ int s[256];
    const int t = threadIdx.x;
    const int i = blockIdx.x * 256 + t;
    const int v = (i < M) ? (int)(packed_in[i] >> 32) : 0;
    s[t] = v;
    __syncthreads();
    for (int o = 1; o < 256; o <<= 1) {
        const int u = (t >= o) ? s[t - o] : 0;
        __syncthreads();
        s[t] += u;
        __syncthreads();
    }
    if (i < M) off_in[i] = bsum[blockIdx.x] + s[t] - v;
}

// ---------------------------------------------------------------------------
// K3: edge_lcs_fill — 4 edges/wave, 16 lanes/edge.
// ---------------------------------------------------------------------------
__global__ __launch_bounds__(THREADS)
void edge_lcs_fill(const ushort* __restrict__ Pb,
                   const int* __restrict__ src, const int* __restrict__ dst,
                   const float* __restrict__ counts,
                   const float* __restrict__ W_l2, const float* __restrict__ b_l2,
                   const int* __restrict__ off_in, int* __restrict__ cur_in,
                   float* __restrict__ w_e, float2* __restrict__ uw_in, int E)
{
    const int lane = threadIdx.x & 63;
    const int wid  = threadIdx.x >> 6;
    const int g    = lane >> 4;
    const int gl   = lane & 15;
    int e = (blockIdx.x * 4 + wid) * 4 + g;
    const bool valid = (e < E);
    if (!valid) e = E - 1;

    const int   s = src[e];
    const int   d = dst[e];
    const float c = counts[e];

    const uint* rs = (const uint*)Pb + (size_t)s * 256;
    const uint* rd = (const uint*)Pb + (size_t)d * 256;

    const uint4 av = ((const uint4*)(rs + 128))[gl];   // a  : elems 256..383
    const uint4 bv = ((const uint4*)(rd + 192))[gl];   // bb : elems 384..511

    const float4 wa = ((const float4*)W_l2)[gl * 2];
    const float4 wb = ((const float4*)W_l2)[gl * 2 + 1];

    float part =
        fmaxf(blo(av.x) + blo(bv.x), 0.f) * wa.x + fmaxf(bhi(av.x) + bhi(bv.x), 0.f) * wa.y +
        fmaxf(blo(av.y) + blo(bv.y), 0.f) * wa.z + fmaxf(bhi(av.y) + bhi(bv.y), 0.f) * wa.w +
        fmaxf(blo(av.z) + blo(bv.z), 0.f) * wb.x + fmaxf(bhi(av.z) + bhi(bv.z), 0.f) * wb.y +
        fmaxf(blo(av.w) + blo(bv.w), 0.f) * wb.z + fmaxf(bhi(av.w) + bhi(bv.w), 0.f) * wb.w;

    part += __shfl_xor(part, 1);
    part += __shfl_xor(part, 2);
    part += __shfl_xor(part, 4);
    part += __shfl_xor(part, 8);

    if (gl == 0 && valid) {
        const float lcs = 1.f / (1.f + expf(-(part + b_l2[0])));
        const float w   = lcs * c;
        w_e[e] = w;
        const int r1 = atomicAdd(cur_in + d, 1);
        uw_in[off_in[d] + r1] = make_float2(__int_as_float(s), w);
    }
}

// ---------------------------------------------------------------------------
// K4: node_agg — 1 wave per (node,dir), 4 edge-groups of 16 lanes.
// ---------------------------------------------------------------------------
__global__ __launch_bounds__(THREADS)
void node_agg(ushort* __restrict__ Pb,
              const float2* __restrict__ uw_in,
              const int* __restrict__ off_in, const ull* __restrict__ packed_in,
              const int* __restrict__ off_out,
              const int* __restrict__ dst, const float* __restrict__ w_e,
              const float* __restrict__ counts, int M)
{
    const int lane = threadIdx.x & 63;
    const int wid  = threadIdx.x >> 6;
    const int task = blockIdx.x * 4 + wid;
    if (task >= 2 * M) return;
    const int v   = task >> 1;
    const int dir = task & 1;

    const int g  = lane >> 4;
    const int gl = lane & 15;

    float a0 = 0.f, a1 = 0.f, a2 = 0.f, a3 = 0.f;
    float a4 = 0.f, a5 = 0.f, a6 = 0.f, a7 = 0.f;
    float dg = 0.f;

    if (dir == 0) {
        const ull pk = packed_in[v];
        const int n  = (int)(pk >> 32);
        dg = (g == 0) ? (float)(uint)(pk & 0xffffffffu) : 0.f;
        const float2* __restrict__ uw = uw_in + off_in[v];
        for (int j = g; j < n; j += 4) {
            const float2 p = uw[j];
            const int    u = __float_as_int(p.x);
            const float  w = p.y;
            const uint4 pv = ((const uint4*)((const uint*)Pb + (size_t)u * 256))[gl];
            a0 = fmaf(blo(pv.x), w, a0); a1 = fmaf(bhi(pv.x), w, a1);
            a2 = fmaf(blo(pv.y), w, a2); a3 = fmaf(bhi(pv.y), w, a3);
            a4 = fmaf(blo(pv.z), w, a4); a5 = fmaf(bhi(pv.z), w, a5);
            a6 = fmaf(blo(pv.w), w, a6); a7 = fmaf(bhi(pv.w), w, a7);
        }
    } else {
        const int base = off_out[v];
        const int end  = off_out[v + 1];
        for (int j = base + g; j < end; j += 4) {
            const int    u = dst[j];
            const float  w = w_e[j];
            dg += counts[j];
            const uint4 pv = ((const uint4*)((const uint*)Pb + (size_t)u * 256 + 64))[gl];
            a0 = fmaf(blo(pv.x), w, a0); a1 = fmaf(bhi(pv.x), w, a1);
            a2 = fmaf(blo(pv.y), w, a2); a3 = fmaf(bhi(pv.y), w, a3);
            a4 = fmaf(blo(pv.z), w, a4); a5 = fmaf(bhi(pv.z), w, a5);
            a6 = fmaf(blo(pv.w), w, a6); a7 = fmaf(bhi(pv.w), w, a7);
        }
    }

#define RED2(a) a += __shfl_xor(a, 16); a += __shfl_xor(a, 32);
    RED2(a0) RED2(a1) RED2(a2) RED2(a3) RED2(a4) RED2(a5) RED2(a6) RED2(a7) RED2(dg)
#undef RED2

    if (g == 0) {
        const float r = 1.f / fmaxf(dg, 1.f);
        uint4 o;
        o.x = packbf(a0 * r, a1 * r);
        o.y = packbf(a2 * r, a3 * r);
        o.z = packbf(a4 * r, a5 * r);
        o.w = packbf(a6 * r, a7 * r);
        ((uint4*)((uint*)Pb + (size_t)v * 256 + (dir ? 192 : 128)))[gl] = o;
    }
}

// ---------------------------------------------------------------------------
// K5: gemm_gate (MFMA) — G = relu([h_in_n|h_out_n] @ W_g1 + b_g1)
// ---------------------------------------------------------------------------
__global__ __launch_bounds__(THREADS)
void gemm_gate(ushort* __restrict__ Pb, int M,
               const ushort* __restrict__ Wtg1, const float* __restrict__ b_g1)
{
    __shared__ __align__(16) char AsB[16384];
    __shared__ __align__(16) char BtB[32768];

    const int tid = threadIdx.x;
    const int m0  = blockIdx.x * 64;
    const int wv = tid >> 6, ln = tid & 63;

    f32x4 acc[8];
#pragma unroll
    for (int tt = 0; tt < 8; ++tt) acc[tt] = (f32x4){0.f, 0.f, 0.f, 0.f};

    for (int h = 0; h < 2; ++h) {
        if (h) __syncthreads();
        {
            const int r = tid >> 2, seg = tid & 3;
            int gr = m0 + r; if (gr >= M) gr = M - 1;
            const uint4* ps = (const uint4*)Pb + (size_t)gr * 64 + 32 + h * 16 + seg * 4;
#pragma unroll
            for (int i = 0; i < 4; ++i) {
                const uint4 u = ps[i];
                const int kbyte = seg * 64 + i * 16;
                *(uint4*)(AsB + r * 256 + (kbyte ^ ((r & 7) << 4))) = u;
            }
        }
        {
            const int rn = tid >> 1, sg = tid & 1;
            const uint4* ws = (const uint4*)Wtg1 + (size_t)rn * 32 + h * 16 + sg * 8;
#pragma unroll
            for (int i = 0; i < 8; ++i) {
                const uint4 u = ws[i];
                const int kbyte = sg * 128 + i * 16;
                *(uint4*)(BtB + rn * 256 + (kbyte ^ ((rn & 7) << 4))) = u;
            }
        }
        __syncthreads();
        mfma_tile_compute(AsB, BtB, wv, ln, acc);
    }

    __syncthreads();
#pragma unroll
    for (int tt = 0; tt < 8; ++tt) {
        const int n = tt * 16 + (ln & 15);
        const float bv = b_g1[n];
#pragma unroll
        for (int r = 0; r < 4; ++r) {
            const int m = wv * 16 + ((ln >> 4) << 2) + r;
            ((ushort*)AsB)[m * 128 + n] = (ushort)bf16r(fmaxf(acc[tt][r] + bv, 0.f));
        }
    }
    __syncthreads();
    {
        const int rr = tid >> 2, sg2 = tid & 3;
        const int gr = m0 + rr;
        if (gr < M) {
            uint4* dstp = (uint4*)Pb + (size_t)gr * 64 + sg2 * 4;
#pragma unroll
            for (int i = 0; i < 4; ++i)
                dstp[i] = *(const uint4*)(AsB + rr * 256 + (sg2 * 4 + i) * 16);
        }
    }
}

// ---------------------------------------------------------------------------
// K6: finalize
// ---------------------------------------------------------------------------
__global__ __launch_bounds__(THREADS)
void finalize(const ushort* __restrict__ Pb,
              const float* __restrict__ W_g2, const float* __restrict__ b_g2,
              const float* __restrict__ x, float* __restrict__ out, int M)
{
    const int lane = threadIdx.x & 63;
    const int wid  = threadIdx.x >> 6;
    const int v    = blockIdx.x * 4 + wid;
    if (v >= M) return;

    const uint* row = (const uint*)Pb + (size_t)v * 256;

    const uint  gv = row[lane];
    const float2 w2 = *(const float2*)(W_g2 + 2 * lane);
    float part = blo(gv) * w2.x + bhi(gv) * w2.y;
#pragma unroll
    for (int off = 32; off; off >>= 1) part += __shfl_xor(part, off);
    const float gate = 1.f / (1.f + expf(-(part + b_g2[0])));

    const uint hiv = row[128 + lane];
    const uint hov = row[192 + lane];
    const float2 xv = *(const float2*)(x + (size_t)v * 128 + 2 * lane);

    float2 o;
    o.x = gate * blo(hiv) + (1.f - gate) * blo(hov) + xv.x;
    o.y = gate * bhi(hiv) + (1.f - gate) * bhi(hov) + xv.y;
    *(float2*)(out + (size_t)v * 128 + 2 * lane) = o;
}

// ---------------------------------------------------------------------------
extern "C" void kernel_launch(void* const* d_in, const int* in_sizes, int n_in,
                              void* d_out, int out_size, void* d_ws, size_t ws_size,
                              hipStream_t stream)
{
    const float* x     = (const float*)d_in[0];
    const int*   src   = (const int*)  d_in[1];
    const int*   dst   = (const int*)  d_in[2];
    const float* cnts  = (const float*)d_in[3];
    const float* W_sd  = (const float*)d_in[4];
    const float* b_sd  = (const float*)d_in[5];
    const float* W_ds  = (const float*)d_in[6];
    const float* b_ds  = (const float*)d_in[7];
    const float* W_l1  = (const float*)d_in[8];
    const float* b_l1  = (const float*)d_in[9];
    const float* W_l2  = (const float*)d_in[10];
    const float* b_l2  = (const float*)d_in[11];
    const float* W_g1  = (const float*)d_in[12];
    const float* b_g1  = (const float*)d_in[13];
    const float* W_g2  = (const float*)d_in[14];
    const float* b_g2  = (const float*)d_in[15];

    const int M = in_sizes[0] / 128;
    const int E = in_sizes[1];

    // workspace:
    //   Pb        : M*512 bf16
    //   Wt        : 4*128*128 bf16
    //   Wtg1      : 128*256 bf16
    //   packed_in : ull[M] (zeroed)   cnt<<32 | int(deg)
    //   cur_in    : int[M] (zeroed)
    //   uw_in     : float2[E]
    //   off_in    : int[M]
    //   off_out   : int[M+1]
    //   w_e       : float[E]
    //   bsum      : int[(M+255)/256]
    ushort* Pb        = (ushort*)d_ws;
    ushort* Wt        = Pb + (size_t)M * 512;
    ushort* Wtg1      = Wt + 4 * 16384;
    ull*    packed_in = (ull*)(Wtg1 + 32768);
    int*    cur_in    = (int*)(packed_in + M);
    float2* uw_in     = (float2*)(cur_in + M);
    int*    off_in    = (int*)(uw_in + E);
    int*    off_out   = off_in + M;
    float*  w_e       = (float*)(off_out + M + 1);
    int*    bsum      = (int*)(w_e + E);

    // zero packed_in + cur_in (contiguous 12*M bytes)
    hipMemsetAsync(packed_in, 0, 12 * (size_t)M, stream);

    transpose_w<<<dim3(16, 6), THREADS, 0, stream>>>(W_sd, W_ds, W_l1, W_g1, Wt, Wtg1);

    const int gx = (M + 63) / 64;
    gemm_node_count<<<dim3(gx, 5), THREADS, 0, stream>>>(
        x, M, Wt, b_sd, b_ds, b_l1, Pb, src, dst, cnts, packed_in, off_out, E);

    const int NB = (M + 255) / 256;     // 196 for M=50000 (must be <= 1024)
    scan_p1<<<NB, 256, 0, stream>>>(packed_in, bsum, M);
    scan_p2<<<1, 1024, 0, stream>>>(bsum, NB);
    scan_p3<<<NB, 256, 0, stream>>>(packed_in, bsum, off_in, M);

    edge_lcs_fill<<<(E + 15) / 16, THREADS, 0, stream>>>(
        Pb, src, dst, cnts, W_l2, b_l2, off_in, cur_in, w_e, uw_in, E);

    node_agg<<<(2 * M + 3) / 4, THREADS, 0, stream>>>(
        Pb, uw_in, off_in, packed_in, off_out, dst, w_e, cnts, M);

    gemm_gate<<<gx, THREADS, 0, stream>>>(Pb, M, Wtg1, b_g1);

    finalize<<<(M + 3) / 4, THREADS, 0, stream>>>(Pb, W_g2, b_g2, x, (float*)d_out, M);
}

// Round 9
// 191.040 us; speedup vs baseline: 5.7427x; 1.1069x over previous
//
#include <hip/hip_runtime.h>
#include <math.h>

typedef unsigned int uint;
typedef unsigned long long ull;

#define THREADS 256
#define NC 96          // counting blocks at head of fused grid

typedef __attribute__((ext_vector_type(8))) short bf16x8;
typedef __attribute__((ext_vector_type(4))) float f32x4;

// ---- bf16 helpers (storage-only; math in fp32 / MFMA-fp32-accum) ----------
__device__ __forceinline__ float blo(uint u) { return __uint_as_float(u << 16); }
__device__ __forceinline__ float bhi(uint u) { return __uint_as_float(u & 0xffff0000u); }
__device__ __forceinline__ uint  bf16r(float x) {           // RTNE
    uint u = __float_as_uint(x);
    return (u + 0x7fffu + ((u >> 16) & 1u)) >> 16;
}
__device__ __forceinline__ uint packbf(float lo, float hi) {
    return bf16r(lo) | (bf16r(hi) << 16);
}

// ---------------------------------------------------------------------------
// K0: transpose weights to bf16 Wt[n][k] once.
// ---------------------------------------------------------------------------
__global__ __launch_bounds__(THREADS)
void transpose_w(const float* __restrict__ W_sd, const float* __restrict__ W_ds,
                 const float* __restrict__ W_l1, const float* __restrict__ W_g1,
                 ushort* __restrict__ Wt, ushort* __restrict__ Wtg1)
{
    __shared__ float tile[32][33];
    const int y = blockIdx.y;
    const float* src;
    ushort* dst;
    int dstK, kofs;
    if (y < 4) {
        src = (y == 0) ? W_sd : (y == 1) ? W_ds : (y == 2) ? W_l1 : (W_l1 + 16384);
        dst = Wt + y * 16384; dstK = 128; kofs = 0;
    } else {
        src = W_g1 + (y - 4) * 16384;
        dst = Wtg1; dstK = 256; kofs = (y - 4) * 128;
    }
    const int tix = blockIdx.x;
    const int k0 = (tix & 3) * 32, n0 = (tix >> 2) * 32;
    const int t = threadIdx.x;

    {
        const int r = t >> 3, c8 = t & 7;
        const float4 f = *(const float4*)(src + (size_t)(k0 + r) * 128 + n0 + c8 * 4);
        tile[r][c8 * 4 + 0] = f.x; tile[r][c8 * 4 + 1] = f.y;
        tile[r][c8 * 4 + 2] = f.z; tile[r][c8 * 4 + 3] = f.w;
    }
    __syncthreads();
    {
        const int n = t >> 3, k8 = t & 7;
        const float v0 = tile[k8 * 4 + 0][n], v1 = tile[k8 * 4 + 1][n];
        const float v2 = tile[k8 * 4 + 2][n], v3 = tile[k8 * 4 + 3][n];
        uint2 o; o.x = packbf(v0, v1); o.y = packbf(v2, v3);
        *(uint2*)(dst + (size_t)(n0 + n) * dstK + kofs + k0 + k8 * 4) = o;
    }
}

// ---------------------------------------------------------------------------
// shared MFMA tile body: As 64x128 bf16 (16KB), Bt 128x128 bf16 (32KB),
// XOR-swizzle kbyte ^= (row&7)<<4 on both; 4 waves x 16 rows x 128 cols.
// ---------------------------------------------------------------------------
__device__ __forceinline__ void mfma_tile_compute(const char* AsB, const char* BtB,
                                                  int wv, int ln, f32x4 acc[8])
{
    const int mrow = wv * 16 + (ln & 15);
    const int kgb  = (ln >> 4) * 16;                 // k-group byte offset
#pragma unroll
    for (int kk = 0; kk < 4; ++kk) {
        const int kbyte = kk * 64 + kgb;
        const bf16x8 a = *(const bf16x8*)(AsB + mrow * 256 + (kbyte ^ ((mrow & 7) << 4)));
#pragma unroll
        for (int tt = 0; tt < 8; ++tt) {
            const int nrow = tt * 16 + (ln & 15);
            const bf16x8 b = *(const bf16x8*)(BtB + nrow * 256 + (kbyte ^ ((nrow & 7) << 4)));
            acc[tt] = __builtin_amdgcn_mfma_f32_16x16x32_bf16(a, b, acc[tt], 0, 0, 0);
        }
    }
}

// ---------------------------------------------------------------------------
// K1 (fused, 1D grid = NC + ceil(M/64)):
//   bid < NC  -> edge counting (1 packed atomic/edge on dst) + off_out fill
//                from SORTED src (np.unique lex order). Grid-stride.
//   bid >= NC -> 64-row strip: stage A once, loop 4 weight groups
//                {stage Bt, MFMA, epilogue}. P[n,0:512] bf16.
// ---------------------------------------------------------------------------
__global__ __launch_bounds__(THREADS)
void gemm_node_count(const float* __restrict__ X, int M,
                     const ushort* __restrict__ Wt,
                     const float* __restrict__ b_sd, const float* __restrict__ b_ds,
                     const float* __restrict__ b_l1,
                     ushort* __restrict__ Pb,
                     const int* __restrict__ src, const int* __restrict__ dst,
                     const float* __restrict__ counts,
                     ull* __restrict__ packed_in, int* __restrict__ off_out,
                     int E)
{
    __shared__ __align__(16) char AsB[16384];
    __shared__ __align__(16) char BtB[32768];

    const int tid = threadIdx.x;
    const int bid = blockIdx.x;

    if (bid < NC) {
        const int stride = NC * THREADS;
        for (int e = bid * THREADS + tid; e < E; e += stride) {
            const int  d = dst[e];
            const uint c = (uint)counts[e];
            atomicAdd(packed_in + d, (1ULL << 32) | (ull)c);
        }
        // off_out: first edge index with src >= v (src sorted non-decreasing)
        for (int e = bid * THREADS + tid; e < E; e += stride) {
            const int cur  = src[e];
            const int prev = (e == 0) ? -1 : src[e - 1];
            for (int v = prev + 1; v <= cur; ++v) off_out[v] = e;
            if (e == E - 1)
                for (int v = cur + 1; v <= M; ++v) off_out[v] = E;
        }
        return;
    }

    const int m0 = (bid - NC) * 64;
    const int wv = tid >> 6, ln = tid & 63;

    // ---- stage A once (64 rows x 128 k, fp32 -> bf16, swizzled) ----
    {
        const int r = tid >> 2, seg = tid & 3;
        int gr = m0 + r; if (gr >= M) gr = M - 1;
        const float4* xs = (const float4*)(X + (size_t)gr * 128 + seg * 32);
#pragma unroll
        for (int i = 0; i < 4; ++i) {
            const float4 f0 = xs[i * 2], f1 = xs[i * 2 + 1];
            uint4 u;
            u.x = packbf(f0.x, f0.y); u.y = packbf(f0.z, f0.w);
            u.z = packbf(f1.x, f1.y); u.w = packbf(f1.z, f1.w);
            const int kbyte = seg * 64 + i * 16;
            *(uint4*)(AsB + r * 256 + (kbyte ^ ((r & 7) << 4))) = u;
        }
    }

    for (int grp = 0; grp < 4; ++grp) {
        // ---- stage Bt(grp) (128 n-rows x 128 k, bf16 from L2, swizzled) ----
        {
            const int rn = tid >> 1, sg = tid & 1;
            const uint4* ws = (const uint4*)(Wt + grp * 16384 + (size_t)rn * 128 + sg * 64);
#pragma unroll
            for (int i = 0; i < 8; ++i) {
                const uint4 u = ws[i];
                const int kbyte = sg * 128 + i * 16;
                *(uint4*)(BtB + rn * 256 + (kbyte ^ ((rn & 7) << 4))) = u;
            }
        }
        __syncthreads();                       // Bt (and A on first iter) ready

        f32x4 acc[8];
#pragma unroll
        for (int tt = 0; tt < 8; ++tt) acc[tt] = (f32x4){0.f, 0.f, 0.f, 0.f};
        mfma_tile_compute(AsB, BtB, wv, ln, acc);
        __syncthreads();                       // all BtB reads done

        // ---- epilogue: bias+bf16, bounce via BtB padded (136 ushort/row) ----
        const float* bias = (grp == 0) ? b_sd : (grp == 1) ? b_ds
                          : (grp == 2) ? b_l1 : nullptr;
#pragma unroll
        for (int tt = 0; tt < 8; ++tt) {
            const int n  = tt * 16 + (ln & 15);
            const float bv = bias ? bias[n] : 0.f;
#pragma unroll
            for (int r = 0; r < 4; ++r) {
                const int m = wv * 16 + ((ln >> 4) << 2) + r;
                ((ushort*)BtB)[m * 136 + n] = (ushort)bf16r(acc[tt][r] + bv);
            }
        }
        __syncthreads();
        {
            const int rr = tid >> 2, sg2 = tid & 3;
            const int gr = m0 + rr;
            if (gr < M) {
                uint4* dstp = (uint4*)Pb + (size_t)gr * 64 + grp * 16 + sg2 * 4;
#pragma unroll
                for (int i = 0; i < 4; ++i)
                    dstp[i] = *(const uint4*)(BtB + rr * 272 + (sg2 * 4 + i) * 16);
            }
        }
        __syncthreads();                       // BtB free for next group
    }
}

// ---------------------------------------------------------------------------
// K2a/b/c: hierarchical exclusive scan of hi32(packed_in) -> off_in.
// ---------------------------------------------------------------------------
__global__ __launch_bounds__(256)
void scan_p1(const ull* __restrict__ packed_in, int* __restrict__ bsum, int M)
{
    __shared__ int s[256];
    const int t = threadIdx.x;
    const int i = blockIdx.x * 256 + t;
    s[t] = (i < M) ? (int)(packed_in[i] >> 32) : 0;
    __syncthreads();
#pragma unroll
    for (int o = 128; o; o >>= 1) {
        if (t < o) s[t] += s[t + o];
        __syncthreads();
    }
    if (t == 0) bsum[blockIdx.x] = s[0];
}

__global__ __launch_bounds__(1024)
void scan_p2(int* __restrict__ bsum, int NB)
{
    __shared__ int s[1024];
    const int t = threadIdx.x;
    const int v = (t < NB) ? bsum[t] : 0;
    s[t] = v;
    __syncthreads();
    for (int o = 1; o < 1024; o <<= 1) {
        const int u = (t >= o) ? s[t - o] : 0;
        __syncthreads();
        s[t] += u;
        __syncthreads();
    }
    if (t < NB) bsum[t] = s[t] - v;   // exclusive
}

__global__ __launch_bounds__(256)
void scan_p3(const ull* __restrict__ packed_in, const int* __restrict__ bsum,
             int* __restrict__ off_in, int M)
{
    __shared__ int s[256];
    const int t = threadIdx.x;
    const int i = blockIdx.x * 256 + t;
    const int v = (i < M) ? (int)(packed_in[i] >> 32) : 0;
    s[t] = v;
    __syncthreads();
    for (int o = 1; o < 256; o <<= 1) {
        const int u = (t >= o) ? s[t - o] : 0;
        __syncthreads();
        s[t] += u;
        __syncthreads();
    }
    if (i < M) off_in[i] = bsum[blockIdx.x] + s[t] - v;
}

// ---------------------------------------------------------------------------
// K3: edge_lcs_fill — 4 edges/wave, 16 lanes/edge.
// ---------------------------------------------------------------------------
__global__ __launch_bounds__(THREADS)
void edge_lcs_fill(const ushort* __restrict__ Pb,
                   const int* __restrict__ src, const int* __restrict__ dst,
                   const float* __restrict__ counts,
                   const float* __restrict__ W_l2, const float* __restrict__ b_l2,
                   const int* __restrict__ off_in, int* __restrict__ cur_in,
                   float* __restrict__ w_e, float2* __restrict__ uw_in, int E)
{
    const int lane = threadIdx.x & 63;
    const int wid  = threadIdx.x >> 6;
    const int g    = lane >> 4;
    const int gl   = lane & 15;
    int e = (blockIdx.x * 4 + wid) * 4 + g;
    const bool valid = (e < E);
    if (!valid) e = E - 1;

    const int   s = src[e];
    const int   d = dst[e];
    const float c = counts[e];

    const uint* rs = (const uint*)Pb + (size_t)s * 256;
    const uint* rd = (const uint*)Pb + (size_t)d * 256;

    const uint4 av = ((const uint4*)(rs + 128))[gl];   // a  : elems 256..383
    const uint4 bv = ((const uint4*)(rd + 192))[gl];   // bb : elems 384..511

    const float4 wa = ((const float4*)W_l2)[gl * 2];
    const float4 wb = ((const float4*)W_l2)[gl * 2 + 1];

    float part =
        fmaxf(blo(av.x) + blo(bv.x), 0.f) * wa.x + fmaxf(bhi(av.x) + bhi(bv.x), 0.f) * wa.y +
        fmaxf(blo(av.y) + blo(bv.y), 0.f) * wa.z + fmaxf(bhi(av.y) + bhi(bv.y), 0.f) * wa.w +
        fmaxf(blo(av.z) + blo(bv.z), 0.f) * wb.x + fmaxf(bhi(av.z) + bhi(bv.z), 0.f) * wb.y +
        fmaxf(blo(av.w) + blo(bv.w), 0.f) * wb.z + fmaxf(bhi(av.w) + bhi(bv.w), 0.f) * wb.w;

    part += __shfl_xor(part, 1);
    part += __shfl_xor(part, 2);
    part += __shfl_xor(part, 4);
    part += __shfl_xor(part, 8);

    if (gl == 0 && valid) {
        const float lcs = 1.f / (1.f + expf(-(part + b_l2[0])));
        const float w   = lcs * c;
        w_e[e] = w;
        const int r1 = atomicAdd(cur_in + d, 1);
        uw_in[off_in[d] + r1] = make_float2(__int_as_float(s), w);
    }
}

// ---------------------------------------------------------------------------
// K4: node_agg — 1 wave per (node,dir), 4 edge-groups of 16 lanes.
// ---------------------------------------------------------------------------
__global__ __launch_bounds__(THREADS)
void node_agg(ushort* __restrict__ Pb,
              const float2* __restrict__ uw_in,
              const int* __restrict__ off_in, const ull* __restrict__ packed_in,
              const int* __restrict__ off_out,
              const int* __restrict__ dst, const float* __restrict__ w_e,
              const float* __restrict__ counts, int M)
{
    const int lane = threadIdx.x & 63;
    const int wid  = threadIdx.x >> 6;
    const int task = blockIdx.x * 4 + wid;
    if (task >= 2 * M) return;
    const int v   = task >> 1;
    const int dir = task & 1;

    const int g  = lane >> 4;
    const int gl = lane & 15;

    float a0 = 0.f, a1 = 0.f, a2 = 0.f, a3 = 0.f;
    float a4 = 0.f, a5 = 0.f, a6 = 0.f, a7 = 0.f;
    float dg = 0.f;

    if (dir == 0) {
        const ull pk = packed_in[v];
        const int n  = (int)(pk >> 32);
        dg = (g == 0) ? (float)(uint)(pk & 0xffffffffu) : 0.f;
        const float2* __restrict__ uw = uw_in + off_in[v];
        for (int j = g; j < n; j += 4) {
            const float2 p = uw[j];
            const int    u = __float_as_int(p.x);
            const float  w = p.y;
            const uint4 pv = ((const uint4*)((const uint*)Pb + (size_t)u * 256))[gl];
            a0 = fmaf(blo(pv.x), w, a0); a1 = fmaf(bhi(pv.x), w, a1);
            a2 = fmaf(blo(pv.y), w, a2); a3 = fmaf(bhi(pv.y), w, a3);
            a4 = fmaf(blo(pv.z), w, a4); a5 = fmaf(bhi(pv.z), w, a5);
            a6 = fmaf(blo(pv.w), w, a6); a7 = fmaf(bhi(pv.w), w, a7);
        }
    } else {
        const int base = off_out[v];
        const int end  = off_out[v + 1];
        for (int j = base + g; j < end; j += 4) {
            const int    u = dst[j];
            const float  w = w_e[j];
            dg += counts[j];
            const uint4 pv = ((const uint4*)((const uint*)Pb + (size_t)u * 256 + 64))[gl];
            a0 = fmaf(blo(pv.x), w, a0); a1 = fmaf(bhi(pv.x), w, a1);
            a2 = fmaf(blo(pv.y), w, a2); a3 = fmaf(bhi(pv.y), w, a3);
            a4 = fmaf(blo(pv.z), w, a4); a5 = fmaf(bhi(pv.z), w, a5);
            a6 = fmaf(blo(pv.w), w, a6); a7 = fmaf(bhi(pv.w), w, a7);
        }
    }

#define RED2(a) a += __shfl_xor(a, 16); a += __shfl_xor(a, 32);
    RED2(a0) RED2(a1) RED2(a2) RED2(a3) RED2(a4) RED2(a5) RED2(a6) RED2(a7) RED2(dg)
#undef RED2

    if (g == 0) {
        const float r = 1.f / fmaxf(dg, 1.f);
        uint4 o;
        o.x = packbf(a0 * r, a1 * r);
        o.y = packbf(a2 * r, a3 * r);
        o.z = packbf(a4 * r, a5 * r);
        o.w = packbf(a6 * r, a7 * r);
        ((uint4*)((uint*)Pb + (size_t)v * 256 + (dir ? 192 : 128)))[gl] = o;
    }
}

// ---------------------------------------------------------------------------
// K5: gemm_gate (MFMA) — G = relu([h_in_n|h_out_n] @ W_g1 + b_g1)
// ---------------------------------------------------------------------------
__global__ __launch_bounds__(THREADS)
void gemm_gate(ushort* __restrict__ Pb, int M,
               const ushort* __restrict__ Wtg1, const float* __restrict__ b_g1)
{
    __shared__ __align__(16) char AsB[16384];
    __shared__ __align__(16) char BtB[32768];

    const int tid = threadIdx.x;
    const int m0  = blockIdx.x * 64;
    const int wv = tid >> 6, ln = tid & 63;

    f32x4 acc[8];
#pragma unroll
    for (int tt = 0; tt < 8; ++tt) acc[tt] = (f32x4){0.f, 0.f, 0.f, 0.f};

    for (int h = 0; h < 2; ++h) {
        if (h) __syncthreads();
        {
            const int r = tid >> 2, seg = tid & 3;
            int gr = m0 + r; if (gr >= M) gr = M - 1;
            const uint4* ps = (const uint4*)Pb + (size_t)gr * 64 + 32 + h * 16 + seg * 4;
#pragma unroll
            for (int i = 0; i < 4; ++i) {
                const uint4 u = ps[i];
                const int kbyte = seg * 64 + i * 16;
                *(uint4*)(AsB + r * 256 + (kbyte ^ ((r & 7) << 4))) = u;
            }
        }
        {
            const int rn = tid >> 1, sg = tid & 1;
            const uint4* ws = (const uint4*)Wtg1 + (size_t)rn * 32 + h * 16 + sg * 8;
#pragma unroll
            for (int i = 0; i < 8; ++i) {
                const uint4 u = ws[i];
                const int kbyte = sg * 128 + i * 16;
                *(uint4*)(BtB + rn * 256 + (kbyte ^ ((rn & 7) << 4))) = u;
            }
        }
        __syncthreads();
        mfma_tile_compute(AsB, BtB, wv, ln, acc);
    }

    __syncthreads();                           // BtB reads done; reuse padded
#pragma unroll
    for (int tt = 0; tt < 8; ++tt) {
        const int n = tt * 16 + (ln & 15);
        const float bv = b_g1[n];
#pragma unroll
        for (int r = 0; r < 4; ++r) {
            const int m = wv * 16 + ((ln >> 4) << 2) + r;
            ((ushort*)BtB)[m * 136 + n] = (ushort)bf16r(fmaxf(acc[tt][r] + bv, 0.f));
        }
    }
    __syncthreads();
    {
        const int rr = tid >> 2, sg2 = tid & 3;
        const int gr = m0 + rr;
        if (gr < M) {
            uint4* dstp = (uint4*)Pb + (size_t)gr * 64 + sg2 * 4;
#pragma unroll
            for (int i = 0; i < 4; ++i)
                dstp[i] = *(const uint4*)(BtB + rr * 272 + (sg2 * 4 + i) * 16);
        }
    }
}

// ---------------------------------------------------------------------------
// K6: finalize
// ---------------------------------------------------------------------------
__global__ __launch_bounds__(THREADS)
void finalize(const ushort* __restrict__ Pb,
              const float* __restrict__ W_g2, const float* __restrict__ b_g2,
              const float* __restrict__ x, float* __restrict__ out, int M)
{
    const int lane = threadIdx.x & 63;
    const int wid  = threadIdx.x >> 6;
    const int v    = blockIdx.x * 4 + wid;
    if (v >= M) return;

    const uint* row = (const uint*)Pb + (size_t)v * 256;

    const uint  gv = row[lane];
    const float2 w2 = *(const float2*)(W_g2 + 2 * lane);
    float part = blo(gv) * w2.x + bhi(gv) * w2.y;
#pragma unroll
    for (int off = 32; off; off >>= 1) part += __shfl_xor(part, off);
    const float gate = 1.f / (1.f + expf(-(part + b_g2[0])));

    const uint hiv = row[128 + lane];
    const uint hov = row[192 + lane];
    const float2 xv = *(const float2*)(x + (size_t)v * 128 + 2 * lane);

    float2 o;
    o.x = gate * blo(hiv) + (1.f - gate) * blo(hov) + xv.x;
    o.y = gate * bhi(hiv) + (1.f - gate) * bhi(hov) + xv.y;
    *(float2*)(out + (size_t)v * 128 + 2 * lane) = o;
}

// ---------------------------------------------------------------------------
extern "C" void kernel_launch(void* const* d_in, const int* in_sizes, int n_in,
                              void* d_out, int out_size, void* d_ws, size_t ws_size,
                              hipStream_t stream)
{
    const float* x     = (const float*)d_in[0];
    const int*   src   = (const int*)  d_in[1];
    const int*   dst   = (const int*)  d_in[2];
    const float* cnts  = (const float*)d_in[3];
    const float* W_sd  = (const float*)d_in[4];
    const float* b_sd  = (const float*)d_in[5];
    const float* W_ds  = (const float*)d_in[6];
    const float* b_ds  = (const float*)d_in[7];
    const float* W_l1  = (const float*)d_in[8];
    const float* b_l1  = (const float*)d_in[9];
    const float* W_l2  = (const float*)d_in[10];
    const float* b_l2  = (const float*)d_in[11];
    const float* W_g1  = (const float*)d_in[12];
    const float* b_g1  = (const float*)d_in[13];
    const float* W_g2  = (const float*)d_in[14];
    const float* b_g2  = (const float*)d_in[15];

    const int M = in_sizes[0] / 128;
    const int E = in_sizes[1];

    // workspace:
    //   Pb        : M*512 bf16
    //   Wt        : 4*128*128 bf16
    //   Wtg1      : 128*256 bf16
    //   packed_in : ull[M] (zeroed)   cnt<<32 | int(deg)
    //   cur_in    : int[M] (zeroed)
    //   uw_in     : float2[E]
    //   off_in    : int[M]
    //   off_out   : int[M+1]
    //   w_e       : float[E]
    //   bsum      : int[(M+255)/256]
    ushort* Pb        = (ushort*)d_ws;
    ushort* Wt        = Pb + (size_t)M * 512;
    ushort* Wtg1      = Wt + 4 * 16384;
    ull*    packed_in = (ull*)(Wtg1 + 32768);
    int*    cur_in    = (int*)(packed_in + M);
    float2* uw_in     = (float2*)(cur_in + M);
    int*    off_in    = (int*)(uw_in + E);
    int*    off_out   = off_in + M;
    float*  w_e       = (float*)(off_out + M + 1);
    int*    bsum      = (int*)(w_e + E);

    // zero packed_in + cur_in (contiguous 12*M bytes)
    hipMemsetAsync(packed_in, 0, 12 * (size_t)M, stream);

    transpose_w<<<dim3(16, 6), THREADS, 0, stream>>>(W_sd, W_ds, W_l1, W_g1, Wt, Wtg1);

    const int gx = (M + 63) / 64;
    gemm_node_count<<<NC + gx, THREADS, 0, stream>>>(
        x, M, Wt, b_sd, b_ds, b_l1, Pb, src, dst, cnts, packed_in, off_out, E);

    const int NB = (M + 255) / 256;     // 196 for M=50000 (must be <= 1024)
    scan_p1<<<NB, 256, 0, stream>>>(packed_in, bsum, M);
    scan_p2<<<1, 1024, 0, stream>>>(bsum, NB);
    scan_p3<<<NB, 256, 0, stream>>>(packed_in, bsum, off_in, M);

    edge_lcs_fill<<<(E + 15) / 16, THREADS, 0, stream>>>(
        Pb, src, dst, cnts, W_l2, b_l2, off_in, cur_in, w_e, uw_in, E);

    node_agg<<<(2 * M + 3) / 4, THREADS, 0, stream>>>(
        Pb, uw_in, off_in, packed_in, off_out, dst, w_e, cnts, M);

    gemm_gate<<<gx, THREADS, 0, stream>>>(Pb, M, Wtg1, b_g1);

    finalize<<<(M + 3) / 4, THREADS, 0, stream>>>(Pb, W_g2, b_g2, x, (float*)d_out, M);
}